// Round 7
// baseline (396.762 us; speedup 1.0000x reference)
//
#include <hip/hip_runtime.h>
#include <hip/hip_bf16.h>
#include <stdint.h>

typedef unsigned short u16;
typedef short short8 __attribute__((ext_vector_type(8)));
typedef float floatx4 __attribute__((ext_vector_type(4)));
typedef float floatx16 __attribute__((ext_vector_type(16)));

#define S_LEN 2048
#define NB 2
#define NH 8
#define R_TOK (NB * S_LEN)  // 4096

#define L2_THETA 13.287712379549449f
// attention scale folded into Q, log2 domain: (1/sqrt(128)) * log2(e)
#define QSCALE (0.08838834764831845f * 1.4426950408889634f)

__device__ inline u16 f2bf(float f) {
  union { float f; uint32_t u; } x; x.f = f;
  uint32_t r = (x.u + 0x7fffu + ((x.u >> 16) & 1u)) >> 16;
  return (u16)r;
}
__device__ inline float bf2f(u16 h) {
  union { uint32_t u; float f; } x; x.u = ((uint32_t)h) << 16;
  return x.f;
}
__device__ inline floatx4 mfma16(short8 a, short8 b, floatx4 c) {
  return __builtin_amdgcn_mfma_f32_16x16x32_bf16(a, b, c, 0, 0, 0);
}
__device__ inline floatx16 mfma32(short8 a, short8 b, floatx16 c) {
  return __builtin_amdgcn_mfma_f32_32x32x16_bf16(a, b, c, 0, 0, 0);
}
__device__ inline uint32_t pkbf(float a, float b) {
  union { __hip_bfloat162 h; uint32_t u; } c;
  c.h = __float22bfloat162_rn(make_float2(a, b));
  return c.u;
}
__device__ __forceinline__ void cp16(const void* g, const void* l) {
  __builtin_amdgcn_global_load_lds(
      (const __attribute__((address_space(1))) uint32_t*)(uintptr_t)g,
      (__attribute__((address_space(3))) uint32_t*)(uintptr_t)l, 16, 0, 0);
}

// ---------------- fused prep: x->bf16, weight transposes, bias concat ----------------
__global__ __launch_bounds__(256) void k_prep(
    const float* __restrict__ x, u16* __restrict__ xbf,
    const float* __restrict__ wdq, const float* __restrict__ wdkv, u16* __restrict__ waT,
    const float* __restrict__ wuq, u16* __restrict__ wQT,
    const float* __restrict__ wukv, u16* __restrict__ wKVT,
    const float* __restrict__ wo, u16* __restrict__ wOT,
    const float* __restrict__ bdq, const float* __restrict__ bdkv,
    float* __restrict__ biasA) {
  __shared__ u16 tile[32][33];
  const int s = blockIdx.x, tid = threadIdx.x;
  const int tx = tid & 31, ty = tid >> 5;
  if (s < 4096) {
    int i = s * 256 + tid;
    float4 v = ((const float4*)x)[i];
    ushort4 o;
    o.x = f2bf(v.x); o.y = f2bf(v.y); o.z = f2bf(v.z); o.w = f2bf(v.w);
    ((ushort4*)xbf)[i] = o;
  } else if (s < 4416) {  // waT: logical [1024][320] -> [320][1024]
    int t = s - 4096, bx = t % 10, by = t / 10;
    int c0 = bx * 32, r0 = by * 32;
#pragma unroll
    for (int i = 0; i < 4; ++i) {
      int r = r0 + ty + i * 8, c = c0 + tx;
      float v = (c < 128) ? wdq[(size_t)r * 128 + c] : wdkv[(size_t)r * 192 + (c - 128)];
      tile[ty + i * 8][tx] = f2bf(v);
    }
    __syncthreads();
#pragma unroll
    for (int i = 0; i < 4; ++i)
      waT[(size_t)(c0 + ty + i * 8) * 1024 + r0 + tx] = tile[tx][ty + i * 8];
  } else {
    const float* in; u16* out; int R, C, bx, by;
    if (s < 4544) { int t = s - 4416; in = wuq; out = wQT; R = 128; C = 1024; bx = t & 31; by = t >> 5; }
    else if (s < 4864) { int t = s - 4544; in = wukv; out = wKVT; R = 128; C = 2560; bx = t % 80; by = t / 80; }
    else if (s < 6912) { int t = s - 4864; in = wo; out = wOT; R = 2048; C = 1024; bx = t & 31; by = t >> 5; }
    else {
      if (tid < 320) biasA[tid] = (tid < 128) ? bdq[tid] : bdkv[tid - 128];
      return;
    }
    int c0 = bx * 32, r0 = by * 32;
#pragma unroll
    for (int i = 0; i < 4; ++i)
      tile[ty + i * 8][tx] = f2bf(in[(size_t)(r0 + ty + i * 8) * C + c0 + tx]);
    __syncthreads();
#pragma unroll
    for (int i = 0; i < 4; ++i)
      out[(size_t)(c0 + ty + i * 8) * R + r0 + tx] = tile[tx][ty + i * 8];
  }
}

// ---------------- 128x128-tile GEMM, B transposed [N][K], double-buffered async ----------
// MODE 0: fp32 out + bias. MODE 2: stage-A fusion (bx0: rmsnorm->cq; bx1: rmsnorm->ckv;
// bx2: rope->krope). aux: nw0=q_norm_w, nw1=kv_norm_w, o0=cq, o1=ckv, o2=krope.
template <int MODE>
__global__ __launch_bounds__(256) void k_gemm(const u16* __restrict__ A,
                                              const u16* __restrict__ BT,
                                              const float* __restrict__ bias,
                                              float* __restrict__ Cout,
                                              int M, int N, int K,
                                              const float* __restrict__ nw0,
                                              const float* __restrict__ nw1,
                                              u16* __restrict__ o0, u16* __restrict__ o1,
                                              u16* __restrict__ o2,
                                              const int* __restrict__ pos) {
  __shared__ __align__(16) u16 Alds[2][128 * 32];
  __shared__ __align__(16) u16 Blds[2][128 * 32];
  const int tid = threadIdx.x;
  const int wave = tid >> 6, lane = tid & 63;
  const int lane15 = lane & 15, quad = lane >> 4;
  const int m0 = blockIdx.y * 128, n0 = blockIdx.x * 128;
  const int mw = (wave & 1) * 64, nw = (wave >> 1) * 64;

  floatx4 acc[4][4];
#pragma unroll
  for (int a = 0; a < 4; ++a)
#pragma unroll
    for (int b = 0; b < 4; ++b) acc[a][b] = (floatx4){0.f, 0.f, 0.f, 0.f};

  const int srow = wave * 32 + (lane >> 2);
  const int scol = (lane & 3) * 8;

  auto stage = [&](int k0, int buf) {
    const u16* ga = A + (size_t)(m0 + srow) * K + k0 + scol;
    cp16(ga, Alds[buf] + srow * 32 + scol);
    cp16(ga + (size_t)16 * K, Alds[buf] + (srow + 16) * 32 + scol);
    const u16* gb = BT + (size_t)(n0 + srow) * K + k0 + scol;
    cp16(gb, Blds[buf] + srow * 32 + scol);
    cp16(gb + (size_t)16 * K, Blds[buf] + (srow + 16) * 32 + scol);
  };

  stage(0, 0);
  int cur = 0;
  for (int k0 = 0; k0 < K; k0 += 32) {
    __syncthreads();
    if (k0 + 32 < K) stage(k0 + 32, cur ^ 1);
    short8 af[4], bf[4];
#pragma unroll
    for (int im = 0; im < 4; ++im)
      af[im] = *(const short8*)&Alds[cur][(mw + im * 16 + lane15) * 32 + quad * 8];
#pragma unroll
    for (int in = 0; in < 4; ++in)
      bf[in] = *(const short8*)&Blds[cur][(nw + in * 16 + lane15) * 32 + quad * 8];
#pragma unroll
    for (int im = 0; im < 4; ++im)
#pragma unroll
      for (int in = 0; in < 4; ++in) acc[im][in] = mfma16(af[im], bf[in], acc[im][in]);
    cur ^= 1;
  }

  if (MODE == 0) {
#pragma unroll
    for (int im = 0; im < 4; ++im)
#pragma unroll
      for (int in = 0; in < 4; ++in)
#pragma unroll
        for (int r = 0; r < 4; ++r) {
          int row = m0 + mw + im * 16 + quad * 4 + r;
          int col = n0 + nw + in * 16 + lane15;
          if (col < N) Cout[(size_t)row * N + col] = acc[im][in][r] + bias[col];
        }
  }
  if (MODE == 2) {
    const int bx = blockIdx.x;
    float bcol[4];
#pragma unroll
    for (int in = 0; in < 4; ++in) bcol[in] = bias[n0 + nw + in * 16 + lane15];
    if (bx < 2) {
      const float* nrm = bx ? nw1 : nw0;
      u16* dst = bx ? o1 : o0;
      // per-(im,r) partial sum of squares over this lane's 4 cols, then over 16 lanes
      float part[4][4];
#pragma unroll
      for (int im = 0; im < 4; ++im)
#pragma unroll
        for (int r = 0; r < 4; ++r) {
          float s = 0.f;
#pragma unroll
          for (int in = 0; in < 4; ++in) {
            float v = acc[im][in][r] + bcol[in];
            s += v * v;
          }
          s += __shfl_xor(s, 1); s += __shfl_xor(s, 2);
          s += __shfl_xor(s, 4); s += __shfl_xor(s, 8);
          part[im][r] = s;  // sum over this wave's 64-col half, all 16 lanes equal
        }
      __syncthreads();  // LDS free (all MFMA reads done)
      float* scratch = (float*)&Alds[0][0];  // [2 halves][128 rows]
      if (lane15 == 0) {
#pragma unroll
        for (int im = 0; im < 4; ++im)
#pragma unroll
          for (int r = 0; r < 4; ++r)
            scratch[(nw >> 6) * 128 + mw + im * 16 + quad * 4 + r] = part[im][r];
      }
      __syncthreads();
#pragma unroll
      for (int im = 0; im < 4; ++im)
#pragma unroll
        for (int r = 0; r < 4; ++r) {
          int row_b = mw + im * 16 + quad * 4 + r;
          float tot = scratch[row_b] + scratch[128 + row_b];
          float ra = rsqrtf(tot * (1.0f / 128.0f) + 1e-8f);
#pragma unroll
          for (int in = 0; in < 4; ++in) {
            int dim = nw + in * 16 + lane15;
            float v = acc[im][in][r] + bcol[in];
            dst[(size_t)(m0 + row_b) * 128 + dim] = f2bf(nrm[dim] * v * ra);
          }
        }
    } else if (nw == 0) {  // bx==2: krope (cols 256..319), only nw=0 waves valid
#pragma unroll
      for (int im = 0; im < 4; ++im)
#pragma unroll
        for (int r = 0; r < 4; ++r) {
          int row = m0 + mw + im * 16 + quad * 4 + r;
          float p = (float)pos[row];
#pragma unroll
          for (int in = 0; in < 4; ++in) {
            int d = in * 16 + lane15;  // 0..63
            float v = acc[im][in][r] + bcol[in];
            float other = __shfl_xor(v, 1);
            int pr = d >> 1;
            float freq = exp2f(-(float)pr * (1.0f / 32.0f) * L2_THETA);
            float ang = p * freq;
            float c = cosf(ang), sn = sinf(ang);
            float outv = (d & 1) ? (other * sn + v * c) : (v * c - other * sn);
            o2[(size_t)row * 64 + d] = f2bf(outv);
          }
        }
    }
  }
}

// ---------------- merged Q-up + KV-up projections (K=128), fused Q epilogue ----------------
__global__ __launch_bounds__(256) void k_qkv(const u16* __restrict__ cq,
                                             const u16* __restrict__ wQT,
                                             const float* __restrict__ buq,
                                             const u16* __restrict__ ckv,
                                             const u16* __restrict__ wKVT,
                                             const float* __restrict__ bukv,
                                             u16* __restrict__ qst, u16* __restrict__ kvb,
                                             const int* __restrict__ pos) {
  __shared__ __align__(16) u16 Alds[2][128 * 32];
  __shared__ __align__(16) u16 Blds[2][128 * 32];
  const int tid = threadIdx.x;
  const int wave = tid >> 6, lane = tid & 63;
  const int lane15 = lane & 15, quad = lane >> 4;
  const int bxe = blockIdx.x;
  const bool isQ = bxe < 8;
  const u16* A = isQ ? cq : ckv;
  const u16* BT = isQ ? wQT : wKVT;
  const float* bias = isQ ? buq : bukv;
  const int N = isQ ? 1024 : 2560;
  const int n0 = (isQ ? bxe : bxe - 8) * 128;
  const int m0 = blockIdx.y * 128;
  const int mw = (wave & 1) * 64, nw = (wave >> 1) * 64;

  floatx4 acc[4][4];
#pragma unroll
  for (int a = 0; a < 4; ++a)
#pragma unroll
    for (int b = 0; b < 4; ++b) acc[a][b] = (floatx4){0.f, 0.f, 0.f, 0.f};

  const int srow = wave * 32 + (lane >> 2);
  const int scol = (lane & 3) * 8;

  auto stage = [&](int k0, int buf) {
    const u16* ga = A + (size_t)(m0 + srow) * 128 + k0 + scol;
    cp16(ga, Alds[buf] + srow * 32 + scol);
    cp16(ga + (size_t)16 * 128, Alds[buf] + (srow + 16) * 32 + scol);
    const u16* gb = BT + (size_t)(n0 + srow) * 128 + k0 + scol;
    cp16(gb, Blds[buf] + srow * 32 + scol);
    cp16(gb + (size_t)16 * 128, Blds[buf] + (srow + 16) * 32 + scol);
  };

  stage(0, 0);
  int cur = 0;
#pragma unroll
  for (int k0 = 0; k0 < 128; k0 += 32) {
    __syncthreads();
    if (k0 + 32 < 128) stage(k0 + 32, cur ^ 1);
    short8 af[4], bf[4];
#pragma unroll
    for (int im = 0; im < 4; ++im)
      af[im] = *(const short8*)&Alds[cur][(mw + im * 16 + lane15) * 32 + quad * 8];
#pragma unroll
    for (int in = 0; in < 4; ++in)
      bf[in] = *(const short8*)&Blds[cur][(nw + in * 16 + lane15) * 32 + quad * 8];
#pragma unroll
    for (int im = 0; im < 4; ++im)
#pragma unroll
      for (int in = 0; in < 4; ++in) acc[im][in] = mfma16(af[im], bf[in], acc[im][in]);
    cur ^= 1;
  }

  if (!isQ) {  // plain bf16 store to kvb
#pragma unroll
    for (int im = 0; im < 4; ++im)
#pragma unroll
      for (int in = 0; in < 4; ++in)
#pragma unroll
        for (int r = 0; r < 4; ++r) {
          int row = m0 + mw + im * 16 + quad * 4 + r;
          int col = n0 + nw + in * 16 + lane15;
          kvb[(size_t)row * 2560 + col] = f2bf(acc[im][in][r] + bias[col]);
        }
  } else {  // Q epilogue: rope + QSCALE + scatter to qst (B,H,S,128)
    const bool ropeBlk = (n0 >= 768);  // blocks 6,7 (block-uniform)
#pragma unroll
    for (int im = 0; im < 4; ++im)
#pragma unroll
      for (int r = 0; r < 4; ++r) {
        int row = m0 + mw + im * 16 + quad * 4 + r;
        int b = row >> 11, s = row & (S_LEN - 1);
        float p = (float)pos[row];
#pragma unroll
        for (int in = 0; in < 4; ++in) {
          int col = n0 + nw + in * 16 + lane15;
          float v = acc[im][in][r] + bias[col];
          int h, d;
          float outv;
          if (!ropeBlk) {
            h = col / 96;
            d = col - h * 96;
            outv = v * QSCALE;
          } else {
            int j2 = col - 768;
            h = j2 >> 5;
            int jj = j2 & 31;
            int pr = jj >> 1;
            float other = __shfl_xor(v, 1);
            float freq = exp2f(-(float)pr * (1.0f / 16.0f) * L2_THETA);
            float ang = p * freq;
            float c = cosf(ang), sn = sinf(ang);
            float rot = (jj & 1) ? (other * sn + v * c) : (v * c - other * sn);
            outv = rot * QSCALE;
            d = 96 + jj;
          }
          qst[((size_t)(b * NH + h) * S_LEN + s) * 128 + d] = f2bf(outv);
        }
      }
  }
}

// ---------------- V transpose with PV k-permutation baked in ----------------
__global__ __launch_bounds__(256) void k_vt(const u16* __restrict__ kvb, u16* __restrict__ vT) {
  __shared__ u16 tile[32][68];
  const int nx = blockIdx.x;   // 0..3
  const int sy = blockIdx.y;   // 0..63
  const int pz = blockIdx.z;   // pair
  const int b = pz >> 3, h = pz & 7;
  const int tid = threadIdx.x;
  const int n0 = nx * 64, s0 = sy * 32;
  {
    int rr = tid >> 4, cc = (tid & 15) * 4;
#pragma unroll
    for (int i = 0; i < 2; ++i) {
      int r = rr + 16 * i;
      const u16* src = kvb + ((size_t)(b * S_LEN + s0 + r)) * 2560 + 512 + h * 256 + n0 + cc;
      ushort4 v = *(const ushort4*)src;
      tile[r][cc] = v.x; tile[r][cc + 1] = v.y; tile[r][cc + 2] = v.z; tile[r][cc + 3] = v.w;
    }
  }
  __syncthreads();
  {
    int nl = tid >> 3, a = tid & 7;
    int p5 = a * 4;
    int k5b = 16 * ((a >> 2) & 1) + 4 * ((a >> 1) & 1) + 8 * (a & 1);
#pragma unroll
    for (int i = 0; i < 2; ++i) {
      int n = nl + 32 * i;
      ushort4 o;
      o.x = tile[k5b][n]; o.y = tile[k5b + 1][n]; o.z = tile[k5b + 2][n]; o.w = tile[k5b + 3][n];
      *(ushort4*)&vT[((size_t)pz * 256 + n0 + n) * 2048 + s0 + p5] = o;
    }
  }
}

// ---------------- flash attention: 32x32x16 MFMA, single-K-buffer pipeline ----------------
// LDS 48KB -> 3 blocks/CU (6 waves). Barrier A drains K(ch) [issued at prev B, PV between];
// then issueV(ch); QK+softmax; barrier B drains V(ch); issueK(ch+1); PV.
__global__ __launch_bounds__(128) void k_attn(const u16* __restrict__ qstates,
                                              const u16* __restrict__ kv,
                                              const u16* __restrict__ krope,
                                              const u16* __restrict__ vT,
                                              u16* __restrict__ attn_out) {
  const int pair = blockIdx.x;
  const int qblk = blockIdx.y;
  const int b = pair >> 3, h = pair & 7;
  const int tid = threadIdx.x;
  const int w = tid >> 6, lane = tid & 63;
  const int l31 = lane & 31, hi = lane >> 5, l15 = lane & 15;

  __shared__ __align__(16) u16 Klds[64 * 128];  // 16 KB, unit-major, u' = u ^ (row&15)
  __shared__ __align__(16) u16 Vlds[256 * 64];  // 32 KB, unit u' = u ^ ((n>>3)&7)

  short8 qfrag[8];
  {
    const u16* qb =
        qstates + ((size_t)(b * NH + h) * S_LEN + qblk * 64 + w * 32 + l31) * 128 + hi * 8;
#pragma unroll
    for (int c = 0; c < 8; ++c) qfrag[c] = *(const short8*)(qb + c * 16);
  }

  floatx16 acc[8];
#pragma unroll
  for (int nt = 0; nt < 8; ++nt)
#pragma unroll
    for (int r = 0; r < 16; ++r) acc[nt][r] = 0.f;
  float m_i = -1e30f, l_i = 0.f;

  const int lr = lane >> 4;
  const u16* kp[4];
  int kstr[4];
#pragma unroll
  for (int p = 0; p < 4; ++p) {
    int row = 32 * w + 4 * p + lr;
    int u = l15 ^ ((4 * p + lr) & 15);
    const u16* base;
    int str;
    if (u < 8) { base = kv + h * 64 + u * 8; str = 2560; }
    else { base = krope + (u - 8) * 8; str = 64; }
    kp[p] = base + (size_t)(b * S_LEN + row) * str;
    kstr[p] = str;
  }
  auto issueK = [&]() {
#pragma unroll
    for (int o = 0; o < 8; ++o) {
      const u16* src = kp[o & 3] + (o >= 4 ? (size_t)16 * kstr[o & 3] : (size_t)0);
      cp16(src, Klds + ((8 * w + o) * 64 + lane) * 8);
    }
#pragma unroll
    for (int p = 0; p < 4; ++p) kp[p] += (size_t)64 * kstr[p];
  };
  const u16* vp = vT + ((size_t)pair * 256 + w * 128 + (lane >> 3)) * 2048;
  auto issueV = [&]() {
#pragma unroll
    for (int oi = 0; oi < 16; ++oi) {
      const u16* src = vp + (size_t)oi * (8 * 2048) + (((lane & 7) ^ (oi & 7)) << 3);
      cp16(src, Vlds + ((w * 128 + oi * 8) * 8 + lane) * 8);
    }
    vp += 64;
  };

  issueK();  // chunk 0

  for (int ch = 0; ch < S_LEN / 64; ++ch) {
    __syncthreads();  // A: drains K(ch); all PV reads of V(ch-1) done
    issueV();         // V(ch), drains at B

    floatx16 st0, st1;
#pragma unroll
    for (int r = 0; r < 16; ++r) { st0[r] = 0.f; st1[r] = 0.f; }
#pragma unroll
    for (int c = 0; c < 8; ++c) {
      int up = (2 * c + hi) ^ l15;
      short8 k0 = *(const short8*)&Klds[l31 * 128 + up * 8];
      short8 k1 = *(const short8*)&Klds[(32 + l31) * 128 + up * 8];
      st0 = mfma32(k0, qfrag[c], st0);
      st1 = mfma32(k1, qfrag[c], st1);
    }

    float mloc = st0[0];
#pragma unroll
    for (int r = 0; r < 16; ++r) { mloc = fmaxf(mloc, st0[r]); mloc = fmaxf(mloc, st1[r]); }
    mloc = fmaxf(mloc, __shfl_xor(mloc, 32));
    float mnew = fmaxf(m_i, mloc);
    float rs = 0.f;
    union { short8 s; uint32_t d[4]; } af[4];
    {
      float pv0[16], pv1[16];
#pragma unroll
      for (int r = 0; r < 16; ++r) { pv0[r] = exp2f(st0[r] - mnew); rs += pv0[r]; }
#pragma unroll
      for (int r = 0; r < 16; ++r) { pv1[r] = exp2f(st1[r] - mnew); rs += pv1[r]; }
#pragma unroll
      for (int s = 0; s < 2; ++s)
#pragma unroll
        for (int d = 0; d < 4; ++d) {
          af[s].d[d] = pkbf(pv0[s * 8 + 2 * d], pv0[s * 8 + 2 * d + 1]);
          af[2 + s].d[d] = pkbf(pv1[s * 8 + 2 * d], pv1[s * 8 + 2 * d + 1]);
        }
    }
    rs += __shfl_xor(rs, 32);

    if (__any(mloc > m_i)) {
      float alpha = exp2f(m_i - mnew);
      l_i = l_i * alpha + rs;
      m_i = mnew;
      float al[16];
#pragma unroll
      for (int r = 0; r < 16; ++r)
        al[r] = __shfl(alpha, (r & 3) + 8 * (r >> 2) + 4 * hi, 32);
#pragma unroll
      for (int nt = 0; nt < 8; ++nt)
#pragma unroll
        for (int r = 0; r < 16; ++r) acc[nt][r] *= al[r];
    } else {
      l_i += rs;
    }

    __syncthreads();  // B: V(ch) drained; all QK reads of K(ch) done
    if (ch + 1 < S_LEN / 64) issueK();  // K(ch+1), drains at next A

#pragma unroll
    for (int nt = 0; nt < 8; ++nt) {
      int n = nt * 32 + l31;
      int sw = (n >> 3) & 7;
      floatx16 o = acc[nt];
#pragma unroll
      for (int m = 0; m < 4; ++m) {
        short8 bf = *(const short8*)&Vlds[n * 64 + (((2 * m + hi) ^ sw) & 7) * 8];
        o = mfma32(af[m].s, bf, o);
      }
      acc[nt] = o;
    }
  }

  float rl = 1.0f / l_i;
  float linv[16];
#pragma unroll
  for (int r = 0; r < 16; ++r)
    linv[r] = __shfl(rl, (r & 3) + 8 * (r >> 2) + 4 * hi, 32);
#pragma unroll
  for (int nt = 0; nt < 8; ++nt)
#pragma unroll
    for (int r = 0; r < 16; ++r) {
      int row = qblk * 64 + w * 32 + (r & 3) + 8 * (r >> 2) + 4 * hi;
      int col = h * 256 + nt * 32 + l31;
      attn_out[((size_t)b * S_LEN + row) * 2048 + col] = f2bf(acc[nt][r] * linv[r]);
    }
}

extern "C" void kernel_launch(void* const* d_in, const int* in_sizes, int n_in,
                              void* d_out, int out_size, void* d_ws, size_t ws_size,
                              hipStream_t stream) {
  const float* x = (const float*)d_in[0];
  const int* pos = (const int*)d_in[1];
  const float* wdq = (const float*)d_in[2];
  const float* bdq = (const float*)d_in[3];
  const float* qnw = (const float*)d_in[4];
  const float* wuq = (const float*)d_in[5];
  const float* buq = (const float*)d_in[6];
  const float* wdkv = (const float*)d_in[7];
  const float* bdkv = (const float*)d_in[8];
  const float* kvnw = (const float*)d_in[9];
  const float* wukv = (const float*)d_in[10];
  const float* bukv = (const float*)d_in[11];
  const float* wo = (const float*)d_in[12];
  const float* bo = (const float*)d_in[13];
  float* out = (float*)d_out;

  char* ws = (char*)d_ws;
  size_t off = 0;
  auto alloc = [&](size_t bytes) {
    char* p = ws + off;
    off += (bytes + 255) & ~(size_t)255;
    return p;
  };
  // vT (16.78MB) aliases xbf (8.39MB): xbf dead after k_gemm<2>, vT written by k_vt later
  u16* vT = (u16*)alloc((size_t)16 * 256 * 2048 * 2);
  u16* xbf = vT;
  u16* waT = (u16*)alloc((size_t)384 * 1024 * 2);  // padded 320->384 rows
  float* biasA = (float*)alloc(320 * 4);
  u16* wQT = (u16*)alloc((size_t)1024 * 128 * 2);
  u16* wKVT = (u16*)alloc((size_t)2560 * 128 * 2);
  u16* wOT = (u16*)alloc((size_t)1024 * 2048 * 2);
  u16* cq = (u16*)alloc((size_t)R_TOK * 128 * 2);
  u16* ckv = (u16*)alloc((size_t)R_TOK * 128 * 2);
  u16* krope = (u16*)alloc((size_t)R_TOK * 64 * 2);
  u16* qst = (u16*)alloc((size_t)R_TOK * 1024 * 2);
  u16* kvb = (u16*)alloc((size_t)R_TOK * 2560 * 2);
  u16* attnb = (u16*)alloc((size_t)R_TOK * 2048 * 2);
  (void)ws_size; (void)n_in; (void)in_sizes; (void)out_size;

  k_prep<<<6913, 256, 0, stream>>>(x, xbf, wdq, wdkv, waT, wuq, wQT, wukv, wKVT, wo, wOT,
                                   bdq, bdkv, biasA);

  // stage A fused: x @ [w_dq|w_dkv_kr] -> rmsnorm/rope -> cq, ckv, krope
  k_gemm<2><<<dim3(3, 32), 256, 0, stream>>>(xbf, waT, biasA, nullptr, R_TOK, 320, 1024,
                                             qnw, kvnw, cq, ckv, krope, pos);
  // merged Q-up (fused rope+scale+scatter -> qst) + KV-up (-> kvb)
  k_qkv<<<dim3(28, 32), 256, 0, stream>>>(cq, wQT, buq, ckv, wKVT, bukv, qst, kvb, pos);
  // V transpose (permuted-k layout); xbf dead here
  k_vt<<<dim3(4, 64, 16), 256, 0, stream>>>(kvb, vT);
  // attention (pair-major grid)
  k_attn<<<dim3(16, 32), 128, 0, stream>>>(qst, kvb, krope, vT, attnb);
  // output projection -> fp32 out
  k_gemm<0><<<dim3(8, 32), 256, 0, stream>>>(attnb, wOT, bo, out, R_TOK, 1024, 2048,
                                             nullptr, nullptr, nullptr, nullptr, nullptr,
                                             nullptr);
}

// Round 8
// 350.164 us; speedup vs baseline: 1.1331x; 1.1331x over previous
//
#include <hip/hip_runtime.h>
#include <hip/hip_bf16.h>
#include <stdint.h>

typedef unsigned short u16;
typedef short short8 __attribute__((ext_vector_type(8)));
typedef float floatx4 __attribute__((ext_vector_type(4)));
typedef float floatx16 __attribute__((ext_vector_type(16)));

#define S_LEN 2048
#define NB 2
#define NH 8
#define R_TOK (NB * S_LEN)  // 4096

#define L2_THETA 13.287712379549449f
// attention scale folded into Q, log2 domain: (1/sqrt(128)) * log2(e)
#define QSCALE (0.08838834764831845f * 1.4426950408889634f)

__device__ inline u16 f2bf(float f) {
  union { float f; uint32_t u; } x; x.f = f;
  uint32_t r = (x.u + 0x7fffu + ((x.u >> 16) & 1u)) >> 16;
  return (u16)r;
}
__device__ inline float bf2f(u16 h) {
  union { uint32_t u; float f; } x; x.u = ((uint32_t)h) << 16;
  return x.f;
}
__device__ inline floatx4 mfma16(short8 a, short8 b, floatx4 c) {
  return __builtin_amdgcn_mfma_f32_16x16x32_bf16(a, b, c, 0, 0, 0);
}
__device__ inline floatx16 mfma32(short8 a, short8 b, floatx16 c) {
  return __builtin_amdgcn_mfma_f32_32x32x16_bf16(a, b, c, 0, 0, 0);
}
__device__ inline uint32_t pkbf(float a, float b) {
  union { __hip_bfloat162 h; uint32_t u; } c;
  c.h = __float22bfloat162_rn(make_float2(a, b));
  return c.u;
}
__device__ __forceinline__ void cp16(const void* g, const void* l) {
  __builtin_amdgcn_global_load_lds(
      (const __attribute__((address_space(1))) uint32_t*)(uintptr_t)g,
      (__attribute__((address_space(3))) uint32_t*)(uintptr_t)l, 16, 0, 0);
}

// ---------------- fused prep: x->bf16, weight transposes, bias concat ----------------
__global__ __launch_bounds__(256) void k_prep(
    const float* __restrict__ x, u16* __restrict__ xbf,
    const float* __restrict__ wdq, const float* __restrict__ wdkv, u16* __restrict__ waT,
    const float* __restrict__ wuq, u16* __restrict__ wQT,
    const float* __restrict__ wukv, u16* __restrict__ wKVT,
    const float* __restrict__ wo, u16* __restrict__ wOT,
    const float* __restrict__ bdq, const float* __restrict__ bdkv,
    float* __restrict__ biasA) {
  __shared__ u16 tile[32][33];
  const int s = blockIdx.x, tid = threadIdx.x;
  const int tx = tid & 31, ty = tid >> 5;
  if (s < 4096) {
    int i = s * 256 + tid;
    float4 v = ((const float4*)x)[i];
    ushort4 o;
    o.x = f2bf(v.x); o.y = f2bf(v.y); o.z = f2bf(v.z); o.w = f2bf(v.w);
    ((ushort4*)xbf)[i] = o;
  } else if (s < 4416) {  // waT: logical [1024][320] -> [320][1024]
    int t = s - 4096, bx = t % 10, by = t / 10;
    int c0 = bx * 32, r0 = by * 32;
#pragma unroll
    for (int i = 0; i < 4; ++i) {
      int r = r0 + ty + i * 8, c = c0 + tx;
      float v = (c < 128) ? wdq[(size_t)r * 128 + c] : wdkv[(size_t)r * 192 + (c - 128)];
      tile[ty + i * 8][tx] = f2bf(v);
    }
    __syncthreads();
#pragma unroll
    for (int i = 0; i < 4; ++i)
      waT[(size_t)(c0 + ty + i * 8) * 1024 + r0 + tx] = tile[tx][ty + i * 8];
  } else {
    const float* in; u16* out; int R, C, bx, by;
    if (s < 4544) { int t = s - 4416; in = wuq; out = wQT; R = 128; C = 1024; bx = t & 31; by = t >> 5; }
    else if (s < 4864) { int t = s - 4544; in = wukv; out = wKVT; R = 128; C = 2560; bx = t % 80; by = t / 80; }
    else if (s < 6912) { int t = s - 4864; in = wo; out = wOT; R = 2048; C = 1024; bx = t & 31; by = t >> 5; }
    else {
      if (tid < 320) biasA[tid] = (tid < 128) ? bdq[tid] : bdkv[tid - 128];
      return;
    }
    int c0 = bx * 32, r0 = by * 32;
#pragma unroll
    for (int i = 0; i < 4; ++i)
      tile[ty + i * 8][tx] = f2bf(in[(size_t)(r0 + ty + i * 8) * C + c0 + tx]);
    __syncthreads();
#pragma unroll
    for (int i = 0; i < 4; ++i)
      out[(size_t)(c0 + ty + i * 8) * R + r0 + tx] = tile[tx][ty + i * 8];
  }
}

// ---------------- 128x128-tile GEMM, B transposed [N][K], double-buffered async ----------
template <int OUT_BF>
__global__ __launch_bounds__(256) void k_gemm_bt(const u16* __restrict__ A,
                                                 const u16* __restrict__ BT,
                                                 const float* __restrict__ bias,
                                                 void* __restrict__ Cout,
                                                 int M, int N, int K) {
  __shared__ __align__(16) u16 Alds[2][128 * 32];
  __shared__ __align__(16) u16 Blds[2][128 * 32];
  const int tid = threadIdx.x;
  const int wave = tid >> 6, lane = tid & 63;
  const int lane15 = lane & 15, quad = lane >> 4;
  const int m0 = blockIdx.y * 128, n0 = blockIdx.x * 128;
  const int mw = (wave & 1) * 64, nw = (wave >> 1) * 64;

  floatx4 acc[4][4];
#pragma unroll
  for (int a = 0; a < 4; ++a)
#pragma unroll
    for (int b = 0; b < 4; ++b) acc[a][b] = (floatx4){0.f, 0.f, 0.f, 0.f};

  const int srow = wave * 32 + (lane >> 2);
  const int scol = (lane & 3) * 8;

  auto stage = [&](int k0, int buf) {
    const u16* ga = A + (size_t)(m0 + srow) * K + k0 + scol;
    cp16(ga, Alds[buf] + srow * 32 + scol);
    cp16(ga + (size_t)16 * K, Alds[buf] + (srow + 16) * 32 + scol);
    const u16* gb = BT + (size_t)(n0 + srow) * K + k0 + scol;
    cp16(gb, Blds[buf] + srow * 32 + scol);
    cp16(gb + (size_t)16 * K, Blds[buf] + (srow + 16) * 32 + scol);
  };

  stage(0, 0);
  int cur = 0;
  for (int k0 = 0; k0 < K; k0 += 32) {
    __syncthreads();
    if (k0 + 32 < K) stage(k0 + 32, cur ^ 1);
    short8 af[4], bf[4];
#pragma unroll
    for (int im = 0; im < 4; ++im)
      af[im] = *(const short8*)&Alds[cur][(mw + im * 16 + lane15) * 32 + quad * 8];
#pragma unroll
    for (int in = 0; in < 4; ++in)
      bf[in] = *(const short8*)&Blds[cur][(nw + in * 16 + lane15) * 32 + quad * 8];
#pragma unroll
    for (int im = 0; im < 4; ++im)
#pragma unroll
      for (int in = 0; in < 4; ++in) acc[im][in] = mfma16(af[im], bf[in], acc[im][in]);
    cur ^= 1;
  }

#pragma unroll
  for (int im = 0; im < 4; ++im)
#pragma unroll
    for (int in = 0; in < 4; ++in)
#pragma unroll
      for (int r = 0; r < 4; ++r) {
        int row = m0 + mw + im * 16 + quad * 4 + r;
        int col = n0 + nw + in * 16 + lane15;
        if (col < N) {
          float v = acc[im][in][r] + bias[col];
          if (OUT_BF)
            ((u16*)Cout)[(size_t)row * N + col] = f2bf(v);
          else
            ((float*)Cout)[(size_t)row * N + col] = v;
        }
      }
}

// ---------------- stage-A epilogue: rmsnorm(cq), rmsnorm(ckv), rope(k_rope) ----------------
__global__ void k_stagea(const float* __restrict__ t0, const float* __restrict__ qnw,
                         const float* __restrict__ kvnw, const int* __restrict__ pos_ids,
                         u16* __restrict__ cq, u16* __restrict__ ckv,
                         u16* __restrict__ krope) {
  int r = blockIdx.x, tid = threadIdx.x;  // 128 threads
  const float* row = t0 + (size_t)r * 320;
  float a = row[tid];
  float b = row[128 + tid];
  float sa = a * a, sb = b * b;
#pragma unroll
  for (int d = 1; d < 64; d <<= 1) {
    sa += __shfl_xor(sa, d);
    sb += __shfl_xor(sb, d);
  }
  __shared__ float red[4];
  if ((tid & 63) == 0) { red[(tid >> 6) * 2] = sa; red[(tid >> 6) * 2 + 1] = sb; }
  __syncthreads();
  sa = red[0] + red[2];
  sb = red[1] + red[3];
  float ra = rsqrtf(sa * (1.0f / 128.0f) + 1e-8f);
  float rb = rsqrtf(sb * (1.0f / 128.0f) + 1e-8f);
  cq[(size_t)r * 128 + tid] = f2bf(qnw[tid] * a * ra);
  ckv[(size_t)r * 128 + tid] = f2bf(kvnw[tid] * b * rb);
  if (tid < 32) {
    float xe = row[256 + 2 * tid], xo = row[256 + 2 * tid + 1];
    float p = (float)pos_ids[r];
    float freq = exp2f(-(2.0f * tid / 64.0f) * L2_THETA);
    float ang = p * freq;
    float c = cosf(ang), s = sinf(ang);
    krope[(size_t)r * 64 + 2 * tid] = f2bf(xe * c - xo * s);
    krope[(size_t)r * 64 + 2 * tid + 1] = f2bf(xe * s + xo * c);
  }
}

// ---------------- stage-B epilogue: rope(q_rope) + scale + scatter ----------------
__global__ void k_stageb(const u16* __restrict__ q, const int* __restrict__ pos_ids,
                         u16* __restrict__ qstates) {
  int r = blockIdx.x, tid = threadIdx.x;  // 256 threads
  int b = r >> 11, s = r & (S_LEN - 1);
  float p = (float)pos_ids[r];
#pragma unroll
  for (int i = 0; i < 4; ++i) {
    int idx = tid + i * 256;
    int h = idx >> 7, d = idx & 127;
    float val;
    if (d < 96) {
      val = bf2f(q[(size_t)r * 1024 + h * 96 + d]);
    } else {
      int j = d - 96, pr = j >> 1;
      float xe = bf2f(q[(size_t)r * 1024 + 768 + h * 32 + 2 * pr]);
      float xo = bf2f(q[(size_t)r * 1024 + 768 + h * 32 + 2 * pr + 1]);
      float freq = exp2f(-(2.0f * pr / 32.0f) * L2_THETA);
      float ang = p * freq;
      float c = cosf(ang), sn = sinf(ang);
      val = (j & 1) ? (xe * sn + xo * c) : (xe * c - xo * sn);
    }
    qstates[((size_t)(b * NH + h) * S_LEN + s) * 128 + d] = f2bf(val * QSCALE);
  }
}

// ---------------- V transpose with PV k-permutation baked in ----------------
__global__ __launch_bounds__(256) void k_vt(const u16* __restrict__ kvb, u16* __restrict__ vT) {
  __shared__ u16 tile[32][68];
  const int nx = blockIdx.x;   // 0..3
  const int sy = blockIdx.y;   // 0..63
  const int pz = blockIdx.z;   // pair
  const int b = pz >> 3, h = pz & 7;
  const int tid = threadIdx.x;
  const int n0 = nx * 64, s0 = sy * 32;
  {
    int rr = tid >> 4, cc = (tid & 15) * 4;
#pragma unroll
    for (int i = 0; i < 2; ++i) {
      int r = rr + 16 * i;
      const u16* src = kvb + ((size_t)(b * S_LEN + s0 + r)) * 2560 + 512 + h * 256 + n0 + cc;
      ushort4 v = *(const ushort4*)src;
      tile[r][cc] = v.x; tile[r][cc + 1] = v.y; tile[r][cc + 2] = v.z; tile[r][cc + 3] = v.w;
    }
  }
  __syncthreads();
  {
    int nl = tid >> 3, a = tid & 7;
    int p5 = a * 4;
    int k5b = 16 * ((a >> 2) & 1) + 4 * ((a >> 1) & 1) + 8 * (a & 1);
#pragma unroll
    for (int i = 0; i < 2; ++i) {
      int n = nl + 32 * i;
      ushort4 o;
      o.x = tile[k5b][n]; o.y = tile[k5b + 1][n]; o.z = tile[k5b + 2][n]; o.w = tile[k5b + 3][n];
      *(ushort4*)&vT[((size_t)pz * 256 + n0 + n) * 2048 + s0 + p5] = o;
    }
  }
}

// ---------------- flash attention: 32x32x16 MFMA, 256 threads, 128 q-rows/block ----------
// Grid (16 pairs, 16 qblks) = 256 blocks = 1/CU -> 8 waves/CU = 2/SIMD (TLP for hiding).
// 4 waves x 32 q-rows. K-chunk 64. K 16KB single-buffer + V 32KB = 48KB.
// Schedule: A drains K(ch) [issued at prev B]; issueV(ch); QK+softmax; B drains V(ch);
// issueK(ch+1); PV. Loads always in flight across compute.
__global__ __launch_bounds__(256, 2) void k_attn(const u16* __restrict__ qstates,
                                                 const u16* __restrict__ kv,
                                                 const u16* __restrict__ krope,
                                                 const u16* __restrict__ vT,
                                                 u16* __restrict__ attn_out) {
  const int pair = blockIdx.x;  // 0..15 (pair-major: XCD locality)
  const int qblk = blockIdx.y;  // 0..15
  const int b = pair >> 3, h = pair & 7;
  const int tid = threadIdx.x;
  const int w = tid >> 6, lane = tid & 63;
  const int l31 = lane & 31, hi = lane >> 5, l15 = lane & 15;

  __shared__ __align__(16) u16 Klds[64 * 128];  // 16 KB, unit-major, slot = u ^ (row&15)
  __shared__ __align__(16) u16 Vlds[256 * 64];  // 32 KB, slot = u ^ ((n>>3)&7)

  short8 qfrag[8];
  {
    const u16* qb =
        qstates + ((size_t)(b * NH + h) * S_LEN + qblk * 128 + w * 32 + l31) * 128 + hi * 8;
#pragma unroll
    for (int c = 0; c < 8; ++c) qfrag[c] = *(const short8*)(qb + c * 16);
  }

  floatx16 acc[8];
#pragma unroll
  for (int nt = 0; nt < 8; ++nt)
#pragma unroll
    for (int r = 0; r < 16; ++r) acc[nt][r] = 0.f;
  float m_i = -1e30f, l_i = 0.f;

  // K staging: wave w covers rows 16w..16w+15; op o: rows 16w+4o+lr, unit l15^(row&15)
  const int lr = lane >> 4;
  const u16* kp[4];
  int kstr[4];
#pragma unroll
  for (int o = 0; o < 4; ++o) {
    int rowc = 16 * w + 4 * o + lr;
    int u = l15 ^ ((4 * o + lr) & 15);
    const u16* base;
    int str;
    if (u < 8) { base = kv + h * 64 + u * 8; str = 2560; }
    else { base = krope + (u - 8) * 8; str = 64; }
    kp[o] = base + (size_t)(b * S_LEN + rowc) * str;
    kstr[o] = str;
  }
  auto issueK = [&]() {
#pragma unroll
    for (int o = 0; o < 4; ++o) {
      cp16(kp[o], Klds + ((16 * w + 4 * o) * 16 + lane) * 8);
      kp[o] += (size_t)64 * kstr[o];
    }
  };
  // V staging: 8 ops/thread; op oi: n = oi*32 + (tid>>3), slot tid&7
  const int vn5 = tid >> 3, vsl = tid & 7;
  const u16* vp[8];
#pragma unroll
  for (int oi = 0; oi < 8; ++oi) {
    int n = oi * 32 + vn5;
    int srcu = vsl ^ ((n >> 3) & 7);
    vp[oi] = vT + ((size_t)pair * 256 + n) * 2048 + srcu * 8;
  }
  auto issueV = [&]() {
#pragma unroll
    for (int oi = 0; oi < 8; ++oi) {
      cp16(vp[oi], Vlds + ((size_t)(oi * 256 + tid)) * 8);
      vp[oi] += 64;
    }
  };

  issueK();  // K(0)

  for (int ch = 0; ch < S_LEN / 64; ++ch) {
    __syncthreads();  // A: K(ch) drained; V(ch-1) PV reads done
    issueV();         // V(ch) in flight across QK+softmax

    floatx16 st0, st1;
#pragma unroll
    for (int r = 0; r < 16; ++r) { st0[r] = 0.f; st1[r] = 0.f; }
#pragma unroll
    for (int c = 0; c < 8; ++c) {
      int up = (2 * c + hi) ^ l15;
      short8 k0 = *(const short8*)&Klds[l31 * 128 + up * 8];
      short8 k1 = *(const short8*)&Klds[(32 + l31) * 128 + up * 8];
      st0 = mfma32(k0, qfrag[c], st0);
      st1 = mfma32(k1, qfrag[c], st1);
    }

    float mloc = st0[0];
#pragma unroll
    for (int r = 0; r < 16; ++r) { mloc = fmaxf(mloc, st0[r]); mloc = fmaxf(mloc, st1[r]); }
    mloc = fmaxf(mloc, __shfl_xor(mloc, 32));
    float mnew = fmaxf(m_i, mloc);
    float rs = 0.f;
    union { short8 s; uint32_t d[4]; } af[4];
    {
      float pv0[16], pv1[16];
#pragma unroll
      for (int r = 0; r < 16; ++r) { pv0[r] = exp2f(st0[r] - mnew); rs += pv0[r]; }
#pragma unroll
      for (int r = 0; r < 16; ++r) { pv1[r] = exp2f(st1[r] - mnew); rs += pv1[r]; }
#pragma unroll
      for (int s = 0; s < 2; ++s)
#pragma unroll
        for (int d = 0; d < 4; ++d) {
          af[s].d[d] = pkbf(pv0[s * 8 + 2 * d], pv0[s * 8 + 2 * d + 1]);
          af[2 + s].d[d] = pkbf(pv1[s * 8 + 2 * d], pv1[s * 8 + 2 * d + 1]);
        }
    }
    rs += __shfl_xor(rs, 32);

    if (__any(mloc > m_i)) {
      float alpha = exp2f(m_i - mnew);
      l_i = l_i * alpha + rs;
      m_i = mnew;
      float al[16];
#pragma unroll
      for (int r = 0; r < 16; ++r)
        al[r] = __shfl(alpha, (r & 3) + 8 * (r >> 2) + 4 * hi, 32);
#pragma unroll
      for (int nt = 0; nt < 8; ++nt)
#pragma unroll
        for (int r = 0; r < 16; ++r) acc[nt][r] *= al[r];
    } else {
      l_i += rs;
    }

    __syncthreads();  // B: V(ch) drained; K(ch) QK reads done
    if (ch + 1 < S_LEN / 64) issueK();  // K(ch+1) in flight across PV

#pragma unroll
    for (int nt = 0; nt < 8; ++nt) {
      int n = nt * 32 + l31;
      int sw = (n >> 3) & 7;
      floatx16 o = acc[nt];
#pragma unroll
      for (int m = 0; m < 4; ++m) {
        short8 bf = *(const short8*)&Vlds[n * 64 + (((2 * m + hi) ^ sw) & 7) * 8];
        o = mfma32(af[m].s, bf, o);
      }
      acc[nt] = o;
    }
  }

  float rl = 1.0f / l_i;
  float linv[16];
#pragma unroll
  for (int r = 0; r < 16; ++r)
    linv[r] = __shfl(rl, (r & 3) + 8 * (r >> 2) + 4 * hi, 32);
#pragma unroll
  for (int nt = 0; nt < 8; ++nt)
#pragma unroll
    for (int r = 0; r < 16; ++r) {
      int row = qblk * 128 + w * 32 + (r & 3) + 8 * (r >> 2) + 4 * hi;
      int col = h * 256 + nt * 32 + l31;
      attn_out[((size_t)b * S_LEN + row) * 2048 + col] = f2bf(acc[nt][r] * linv[r]);
    }
}

extern "C" void kernel_launch(void* const* d_in, const int* in_sizes, int n_in,
                              void* d_out, int out_size, void* d_ws, size_t ws_size,
                              hipStream_t stream) {
  const float* x = (const float*)d_in[0];
  const int* pos = (const int*)d_in[1];
  const float* wdq = (const float*)d_in[2];
  const float* bdq = (const float*)d_in[3];
  const float* qnw = (const float*)d_in[4];
  const float* wuq = (const float*)d_in[5];
  const float* buq = (const float*)d_in[6];
  const float* wdkv = (const float*)d_in[7];
  const float* bdkv = (const float*)d_in[8];
  const float* kvnw = (const float*)d_in[9];
  const float* wukv = (const float*)d_in[10];
  const float* bukv = (const float*)d_in[11];
  const float* wo = (const float*)d_in[12];
  const float* bo = (const float*)d_in[13];
  float* out = (float*)d_out;

  char* ws = (char*)d_ws;
  size_t off = 0;
  auto alloc = [&](size_t bytes) {
    char* p = ws + off;
    off += (bytes + 255) & ~(size_t)255;
    return p;
  };
  // vT (16.78MB) aliases xbf+t0+qout (22MB): all dead before k_vt runs
  u16* xbf = (u16*)alloc((size_t)R_TOK * 1024 * 2);    // dead after gemm A
  float* t0 = (float*)alloc((size_t)R_TOK * 320 * 4);  // dead after stagea
  u16* qout = (u16*)alloc((size_t)R_TOK * 1024 * 2);   // dead after stageb
  u16* vT = (u16*)d_ws;                                // alias of the three above
  u16* waT = (u16*)alloc((size_t)384 * 1024 * 2);      // padded 320->384 rows
  float* biasA = (float*)alloc(320 * 4);
  u16* wQT = (u16*)alloc((size_t)1024 * 128 * 2);
  u16* wKVT = (u16*)alloc((size_t)2560 * 128 * 2);
  u16* wOT = (u16*)alloc((size_t)1024 * 2048 * 2);
  u16* cq = (u16*)alloc((size_t)R_TOK * 128 * 2);
  u16* ckv = (u16*)alloc((size_t)R_TOK * 128 * 2);
  u16* krope = (u16*)alloc((size_t)R_TOK * 64 * 2);
  u16* qst = (u16*)alloc((size_t)R_TOK * 1024 * 2);
  u16* kvb = (u16*)alloc((size_t)R_TOK * 2560 * 2);
  u16* attnb = (u16*)alloc((size_t)R_TOK * 2048 * 2);
  (void)ws_size; (void)n_in; (void)in_sizes; (void)out_size;

  k_prep<<<6913, 256, 0, stream>>>(x, xbf, wdq, wdkv, waT, wuq, wQT, wukv, wKVT, wo, wOT,
                                   bdq, bdkv, biasA);

  // stage A: x @ [w_dq | w_dkv_kr] -> t0 fp32
  k_gemm_bt<0><<<dim3(3, 32), 256, 0, stream>>>(xbf, waT, biasA, t0, R_TOK, 320, 1024);
  k_stagea<<<R_TOK, 128, 0, stream>>>(t0, qnw, kvnw, pos, cq, ckv, krope);
  // stage B: q up-proj, rope+scale+scatter
  k_gemm_bt<1><<<dim3(8, 32), 256, 0, stream>>>(cq, wQT, buq, qout, R_TOK, 1024, 128);
  k_stageb<<<R_TOK, 256, 0, stream>>>(qout, pos, qst);
  // kv up-proj
  k_gemm_bt<1><<<dim3(20, 32), 256, 0, stream>>>(ckv, wKVT, bukv, kvb, R_TOK, 2560, 128);
  // V transpose (permuted-k layout); xbf/t0/qout dead here
  k_vt<<<dim3(4, 64, 16), 256, 0, stream>>>(kvb, vT);
  // attention: 256 blocks (1/CU), 256 threads, 128 q-rows/block
  k_attn<<<dim3(16, 16), 256, 0, stream>>>(qst, kvb, krope, vT, attnb);
  // output projection -> fp32 out
  k_gemm_bt<0><<<dim3(8, 32), 256, 0, stream>>>(attnb, wOT, bo, out, R_TOK, 1024, 2048);
}

// Round 9
// 345.255 us; speedup vs baseline: 1.1492x; 1.0142x over previous
//
#include <hip/hip_runtime.h>
#include <hip/hip_bf16.h>
#include <stdint.h>

typedef unsigned short u16;
typedef short short8 __attribute__((ext_vector_type(8)));
typedef float floatx4 __attribute__((ext_vector_type(4)));
typedef float floatx16 __attribute__((ext_vector_type(16)));

#define S_LEN 2048
#define NB 2
#define NH 8
#define R_TOK (NB * S_LEN)  // 4096

#define L2_THETA 13.287712379549449f
// attention scale folded into Q, log2 domain: (1/sqrt(128)) * log2(e)
#define QSCALE (0.08838834764831845f * 1.4426950408889634f)

__device__ inline u16 f2bf(float f) {
  union { float f; uint32_t u; } x; x.f = f;
  uint32_t r = (x.u + 0x7fffu + ((x.u >> 16) & 1u)) >> 16;
  return (u16)r;
}
__device__ inline float bf2f(u16 h) {
  union { uint32_t u; float f; } x; x.u = ((uint32_t)h) << 16;
  return x.f;
}
__device__ inline floatx4 mfma16(short8 a, short8 b, floatx4 c) {
  return __builtin_amdgcn_mfma_f32_16x16x32_bf16(a, b, c, 0, 0, 0);
}
__device__ inline floatx16 mfma32(short8 a, short8 b, floatx16 c) {
  return __builtin_amdgcn_mfma_f32_32x32x16_bf16(a, b, c, 0, 0, 0);
}
__device__ inline uint32_t pkbf(float a, float b) {
  union { __hip_bfloat162 h; uint32_t u; } c;
  c.h = __float22bfloat162_rn(make_float2(a, b));
  return c.u;
}
__device__ __forceinline__ void cp16(const void* g, const void* l) {
  __builtin_amdgcn_global_load_lds(
      (const __attribute__((address_space(1))) uint32_t*)(uintptr_t)g,
      (__attribute__((address_space(3))) uint32_t*)(uintptr_t)l, 16, 0, 0);
}

// ---------------- fused prep: x->bf16, weight transposes, bias concat ----------------
__global__ __launch_bounds__(256) void k_prep(
    const float* __restrict__ x, u16* __restrict__ xbf,
    const float* __restrict__ wdq, const float* __restrict__ wdkv, u16* __restrict__ waT,
    const float* __restrict__ wuq, u16* __restrict__ wQT,
    const float* __restrict__ wukv, u16* __restrict__ wKVT,
    const float* __restrict__ wo, u16* __restrict__ wOT,
    const float* __restrict__ bdq, const float* __restrict__ bdkv,
    float* __restrict__ biasA) {
  __shared__ u16 tile[32][33];
  const int s = blockIdx.x, tid = threadIdx.x;
  const int tx = tid & 31, ty = tid >> 5;
  if (s < 4096) {
    int i = s * 256 + tid;
    float4 v = ((const float4*)x)[i];
    ushort4 o;
    o.x = f2bf(v.x); o.y = f2bf(v.y); o.z = f2bf(v.z); o.w = f2bf(v.w);
    ((ushort4*)xbf)[i] = o;
  } else if (s < 4416) {  // waT: logical [1024][320] -> [320][1024]
    int t = s - 4096, bx = t % 10, by = t / 10;
    int c0 = bx * 32, r0 = by * 32;
#pragma unroll
    for (int i = 0; i < 4; ++i) {
      int r = r0 + ty + i * 8, c = c0 + tx;
      float v = (c < 128) ? wdq[(size_t)r * 128 + c] : wdkv[(size_t)r * 192 + (c - 128)];
      tile[ty + i * 8][tx] = f2bf(v);
    }
    __syncthreads();
#pragma unroll
    for (int i = 0; i < 4; ++i)
      waT[(size_t)(c0 + ty + i * 8) * 1024 + r0 + tx] = tile[tx][ty + i * 8];
  } else {
    const float* in; u16* out; int R, C, bx, by;
    if (s < 4544) { int t = s - 4416; in = wuq; out = wQT; R = 128; C = 1024; bx = t & 31; by = t >> 5; }
    else if (s < 4864) { int t = s - 4544; in = wukv; out = wKVT; R = 128; C = 2560; bx = t % 80; by = t / 80; }
    else if (s < 6912) { int t = s - 4864; in = wo; out = wOT; R = 2048; C = 1024; bx = t & 31; by = t >> 5; }
    else {
      if (tid < 320) biasA[tid] = (tid < 128) ? bdq[tid] : bdkv[tid - 128];
      return;
    }
    int c0 = bx * 32, r0 = by * 32;
#pragma unroll
    for (int i = 0; i < 4; ++i)
      tile[ty + i * 8][tx] = f2bf(in[(size_t)(r0 + ty + i * 8) * C + c0 + tx]);
    __syncthreads();
#pragma unroll
    for (int i = 0; i < 4; ++i)
      out[(size_t)(c0 + ty + i * 8) * R + r0 + tx] = tile[tx][ty + i * 8];
  }
}

// ---------------- 128x128-tile GEMM, B transposed [N][K], double-buffered async ----------
template <int OUT_BF>
__global__ __launch_bounds__(256) void k_gemm_bt(const u16* __restrict__ A,
                                                 const u16* __restrict__ BT,
                                                 const float* __restrict__ bias,
                                                 void* __restrict__ Cout,
                                                 int M, int N, int K) {
  __shared__ __align__(16) u16 Alds[2][128 * 32];
  __shared__ __align__(16) u16 Blds[2][128 * 32];
  const int tid = threadIdx.x;
  const int wave = tid >> 6, lane = tid & 63;
  const int lane15 = lane & 15, quad = lane >> 4;
  const int m0 = blockIdx.y * 128, n0 = blockIdx.x * 128;
  const int mw = (wave & 1) * 64, nw = (wave >> 1) * 64;

  floatx4 acc[4][4];
#pragma unroll
  for (int a = 0; a < 4; ++a)
#pragma unroll
    for (int b = 0; b < 4; ++b) acc[a][b] = (floatx4){0.f, 0.f, 0.f, 0.f};

  const int srow = wave * 32 + (lane >> 2);
  const int scol = (lane & 3) * 8;

  auto stage = [&](int k0, int buf) {
    const u16* ga = A + (size_t)(m0 + srow) * K + k0 + scol;
    cp16(ga, Alds[buf] + srow * 32 + scol);
    cp16(ga + (size_t)16 * K, Alds[buf] + (srow + 16) * 32 + scol);
    const u16* gb = BT + (size_t)(n0 + srow) * K + k0 + scol;
    cp16(gb, Blds[buf] + srow * 32 + scol);
    cp16(gb + (size_t)16 * K, Blds[buf] + (srow + 16) * 32 + scol);
  };

  stage(0, 0);
  int cur = 0;
  for (int k0 = 0; k0 < K; k0 += 32) {
    __syncthreads();
    if (k0 + 32 < K) stage(k0 + 32, cur ^ 1);
    short8 af[4], bf[4];
#pragma unroll
    for (int im = 0; im < 4; ++im)
      af[im] = *(const short8*)&Alds[cur][(mw + im * 16 + lane15) * 32 + quad * 8];
#pragma unroll
    for (int in = 0; in < 4; ++in)
      bf[in] = *(const short8*)&Blds[cur][(nw + in * 16 + lane15) * 32 + quad * 8];
#pragma unroll
    for (int im = 0; im < 4; ++im)
#pragma unroll
      for (int in = 0; in < 4; ++in) acc[im][in] = mfma16(af[im], bf[in], acc[im][in]);
    cur ^= 1;
  }

#pragma unroll
  for (int im = 0; im < 4; ++im)
#pragma unroll
    for (int in = 0; in < 4; ++in)
#pragma unroll
      for (int r = 0; r < 4; ++r) {
        int row = m0 + mw + im * 16 + quad * 4 + r;
        int col = n0 + nw + in * 16 + lane15;
        if (col < N) {
          float v = acc[im][in][r] + bias[col];
          if (OUT_BF)
            ((u16*)Cout)[(size_t)row * N + col] = f2bf(v);
          else
            ((float*)Cout)[(size_t)row * N + col] = v;
        }
      }
}

// ---------------- stage-A epilogue: rmsnorm(cq), rmsnorm(ckv), rope(k_rope) ----------------
__global__ void k_stagea(const float* __restrict__ t0, const float* __restrict__ qnw,
                         const float* __restrict__ kvnw, const int* __restrict__ pos_ids,
                         u16* __restrict__ cq, u16* __restrict__ ckv,
                         u16* __restrict__ krope) {
  int r = blockIdx.x, tid = threadIdx.x;  // 128 threads
  const float* row = t0 + (size_t)r * 320;
  float a = row[tid];
  float b = row[128 + tid];
  float sa = a * a, sb = b * b;
#pragma unroll
  for (int d = 1; d < 64; d <<= 1) {
    sa += __shfl_xor(sa, d);
    sb += __shfl_xor(sb, d);
  }
  __shared__ float red[4];
  if ((tid & 63) == 0) { red[(tid >> 6) * 2] = sa; red[(tid >> 6) * 2 + 1] = sb; }
  __syncthreads();
  sa = red[0] + red[2];
  sb = red[1] + red[3];
  float ra = rsqrtf(sa * (1.0f / 128.0f) + 1e-8f);
  float rb = rsqrtf(sb * (1.0f / 128.0f) + 1e-8f);
  cq[(size_t)r * 128 + tid] = f2bf(qnw[tid] * a * ra);
  ckv[(size_t)r * 128 + tid] = f2bf(kvnw[tid] * b * rb);
  if (tid < 32) {
    float xe = row[256 + 2 * tid], xo = row[256 + 2 * tid + 1];
    float p = (float)pos_ids[r];
    float freq = exp2f(-(2.0f * tid / 64.0f) * L2_THETA);
    float ang = p * freq;
    float c = cosf(ang), s = sinf(ang);
    krope[(size_t)r * 64 + 2 * tid] = f2bf(xe * c - xo * s);
    krope[(size_t)r * 64 + 2 * tid + 1] = f2bf(xe * s + xo * c);
  }
}

// ---------------- stage-B epilogue: rope(q_rope) + scale + scatter ----------------
__global__ void k_stageb(const u16* __restrict__ q, const int* __restrict__ pos_ids,
                         u16* __restrict__ qstates) {
  int r = blockIdx.x, tid = threadIdx.x;  // 256 threads
  int b = r >> 11, s = r & (S_LEN - 1);
  float p = (float)pos_ids[r];
#pragma unroll
  for (int i = 0; i < 4; ++i) {
    int idx = tid + i * 256;
    int h = idx >> 7, d = idx & 127;
    float val;
    if (d < 96) {
      val = bf2f(q[(size_t)r * 1024 + h * 96 + d]);
    } else {
      int j = d - 96, pr = j >> 1;
      float xe = bf2f(q[(size_t)r * 1024 + 768 + h * 32 + 2 * pr]);
      float xo = bf2f(q[(size_t)r * 1024 + 768 + h * 32 + 2 * pr + 1]);
      float freq = exp2f(-(2.0f * pr / 32.0f) * L2_THETA);
      float ang = p * freq;
      float c = cosf(ang), sn = sinf(ang);
      val = (j & 1) ? (xe * sn + xo * c) : (xe * c - xo * sn);
    }
    qstates[((size_t)(b * NH + h) * S_LEN + s) * 128 + d] = f2bf(val * QSCALE);
  }
}

// ---------------- V transpose with PV k-permutation baked in ----------------
__global__ __launch_bounds__(256) void k_vt(const u16* __restrict__ kvb, u16* __restrict__ vT) {
  __shared__ u16 tile[32][68];
  const int nx = blockIdx.x;   // 0..3
  const int sy = blockIdx.y;   // 0..63
  const int pz = blockIdx.z;   // pair
  const int b = pz >> 3, h = pz & 7;
  const int tid = threadIdx.x;
  const int n0 = nx * 64, s0 = sy * 32;
  {
    int rr = tid >> 4, cc = (tid & 15) * 4;
#pragma unroll
    for (int i = 0; i < 2; ++i) {
      int r = rr + 16 * i;
      const u16* src = kvb + ((size_t)(b * S_LEN + s0 + r)) * 2560 + 512 + h * 256 + n0 + cc;
      ushort4 v = *(const ushort4*)src;
      tile[r][cc] = v.x; tile[r][cc + 1] = v.y; tile[r][cc + 2] = v.z; tile[r][cc + 3] = v.w;
    }
  }
  __syncthreads();
  {
    int nl = tid >> 3, a = tid & 7;
    int p5 = a * 4;
    int k5b = 16 * ((a >> 2) & 1) + 4 * ((a >> 1) & 1) + 8 * (a & 1);
#pragma unroll
    for (int i = 0; i < 2; ++i) {
      int n = nl + 32 * i;
      ushort4 o;
      o.x = tile[k5b][n]; o.y = tile[k5b + 1][n]; o.z = tile[k5b + 2][n]; o.w = tile[k5b + 3][n];
      *(ushort4*)&vT[((size_t)pz * 256 + n0 + n) * 2048 + s0 + p5] = o;
    }
  }
}

// ---------------- flash attention: 32x32x16, wave-split q x n, 64 q-rows/block ----------
// 256 threads = 4 waves: wq = w&1 (q half, 32 rows), wn = w>>1 (n half, 128 of 256 dims).
// QK duplicated across wn (+33% MFMA) but acc halves to 4 x floatx16 (64 VGPR) ->
// ~8 waves/CU resident (2 blocks) = 2 waves/SIMD for latency hiding.
// Grid (16 pairs, 32 qblks) = 512 blocks. K 16KB single-buffer + V 32KB = 48KB.
// Schedule: A drains K(ch) [issued at prev B]; issueV(ch); QK+softmax; B drains V(ch);
// issueK(ch+1); PV. NO min-waves launch bound (round-3/8 lesson: it spills).
__global__ __launch_bounds__(256) void k_attn(const u16* __restrict__ qstates,
                                              const u16* __restrict__ kv,
                                              const u16* __restrict__ krope,
                                              const u16* __restrict__ vT,
                                              u16* __restrict__ attn_out) {
  const int pair = blockIdx.x;  // 0..15 (pair-major: XCD locality)
  const int qblk = blockIdx.y;  // 0..31
  const int b = pair >> 3, h = pair & 7;
  const int tid = threadIdx.x;
  const int w = tid >> 6, lane = tid & 63;
  const int wq = w & 1, wn = w >> 1;
  const int l31 = lane & 31, hi = lane >> 5, l15 = lane & 15;

  __shared__ __align__(16) u16 Klds[64 * 128];  // 16 KB, unit-major, slot = u ^ (row&15)
  __shared__ __align__(16) u16 Vlds[256 * 64];  // 32 KB, slot = u ^ ((n>>3)&7)

  short8 qfrag[8];
  {
    const u16* qb =
        qstates + ((size_t)(b * NH + h) * S_LEN + qblk * 64 + wq * 32 + l31) * 128 + hi * 8;
#pragma unroll
    for (int c = 0; c < 8; ++c) qfrag[c] = *(const short8*)(qb + c * 16);
  }

  floatx16 acc[4];
#pragma unroll
  for (int nt = 0; nt < 4; ++nt)
#pragma unroll
    for (int r = 0; r < 16; ++r) acc[nt][r] = 0.f;
  float m_i = -1e30f, l_i = 0.f;

  // K staging: wave w stages rows 16w..16w+15; op o: rows 16w+4o+lr, unit l15^(row&15)
  const int lr = lane >> 4;
  const u16* kp[4];
  int kstr[4];
#pragma unroll
  for (int o = 0; o < 4; ++o) {
    int rowc = 16 * w + 4 * o + lr;
    int u = l15 ^ ((4 * o + lr) & 15);
    const u16* base;
    int str;
    if (u < 8) { base = kv + h * 64 + u * 8; str = 2560; }
    else { base = krope + (u - 8) * 8; str = 64; }
    kp[o] = base + (size_t)(b * S_LEN + rowc) * str;
    kstr[o] = str;
  }
  auto issueK = [&]() {
#pragma unroll
    for (int o = 0; o < 4; ++o) {
      cp16(kp[o], Klds + ((16 * w + 4 * o) * 16 + lane) * 8);
      kp[o] += (size_t)64 * kstr[o];
    }
  };
  // V staging: 8 ops/thread; op oi: n = oi*32 + (tid>>3), slot tid&7
  const int vn5 = tid >> 3, vsl = tid & 7;
  const u16* vp[8];
#pragma unroll
  for (int oi = 0; oi < 8; ++oi) {
    int n = oi * 32 + vn5;
    int srcu = vsl ^ ((n >> 3) & 7);
    vp[oi] = vT + ((size_t)pair * 256 + n) * 2048 + srcu * 8;
  }
  auto issueV = [&]() {
#pragma unroll
    for (int oi = 0; oi < 8; ++oi) {
      cp16(vp[oi], Vlds + ((size_t)(oi * 256 + tid)) * 8);
      vp[oi] += 64;
    }
  };

  issueK();  // K(0)

  for (int ch = 0; ch < S_LEN / 64; ++ch) {
    __syncthreads();  // A: K(ch) drained; V(ch-1) PV reads done
    issueV();         // V(ch) in flight across QK+softmax

    floatx16 st0, st1;
#pragma unroll
    for (int r = 0; r < 16; ++r) { st0[r] = 0.f; st1[r] = 0.f; }
#pragma unroll
    for (int c = 0; c < 8; ++c) {
      int up = (2 * c + hi) ^ l15;
      short8 k0 = *(const short8*)&Klds[l31 * 128 + up * 8];
      short8 k1 = *(const short8*)&Klds[(32 + l31) * 128 + up * 8];
      st0 = mfma32(k0, qfrag[c], st0);
      st1 = mfma32(k1, qfrag[c], st1);
    }

    float mloc = st0[0];
#pragma unroll
    for (int r = 0; r < 16; ++r) { mloc = fmaxf(mloc, st0[r]); mloc = fmaxf(mloc, st1[r]); }
    mloc = fmaxf(mloc, __shfl_xor(mloc, 32));
    float mnew = fmaxf(m_i, mloc);
    float rs = 0.f;
    union { short8 s; uint32_t d[4]; } af[4];
    {
      float pv0[16], pv1[16];
#pragma unroll
      for (int r = 0; r < 16; ++r) { pv0[r] = exp2f(st0[r] - mnew); rs += pv0[r]; }
#pragma unroll
      for (int r = 0; r < 16; ++r) { pv1[r] = exp2f(st1[r] - mnew); rs += pv1[r]; }
#pragma unroll
      for (int s = 0; s < 2; ++s)
#pragma unroll
        for (int d = 0; d < 4; ++d) {
          af[s].d[d] = pkbf(pv0[s * 8 + 2 * d], pv0[s * 8 + 2 * d + 1]);
          af[2 + s].d[d] = pkbf(pv1[s * 8 + 2 * d], pv1[s * 8 + 2 * d + 1]);
        }
    }
    rs += __shfl_xor(rs, 32);

    if (__any(mloc > m_i)) {
      float alpha = exp2f(m_i - mnew);
      l_i = l_i * alpha + rs;
      m_i = mnew;
      float al[16];
#pragma unroll
      for (int r = 0; r < 16; ++r)
        al[r] = __shfl(alpha, (r & 3) + 8 * (r >> 2) + 4 * hi, 32);
#pragma unroll
      for (int nt = 0; nt < 4; ++nt)
#pragma unroll
        for (int r = 0; r < 16; ++r) acc[nt][r] *= al[r];
    } else {
      l_i += rs;
    }

    __syncthreads();  // B: V(ch) drained; K(ch) QK reads done
    if (ch + 1 < S_LEN / 64) issueK();  // K(ch+1) in flight across PV

    // PV for this wave's n-half: n = wn*128 + nt*32 + l31
#pragma unroll
    for (int nt = 0; nt < 4; ++nt) {
      int n = wn * 128 + nt * 32 + l31;
      int sw = (n >> 3) & 7;
      floatx16 o = acc[nt];
#pragma unroll
      for (int m = 0; m < 4; ++m) {
        short8 bf = *(const short8*)&Vlds[n * 64 + (((2 * m + hi) ^ sw) & 7) * 8];
        o = mfma32(af[m].s, bf, o);
      }
      acc[nt] = o;
    }
  }

  float rl = 1.0f / l_i;
  float linv[16];
#pragma unroll
  for (int r = 0; r < 16; ++r)
    linv[r] = __shfl(rl, (r & 3) + 8 * (r >> 2) + 4 * hi, 32);
#pragma unroll
  for (int nt = 0; nt < 4; ++nt)
#pragma unroll
    for (int r = 0; r < 16; ++r) {
      int row = qblk * 64 + wq * 32 + (r & 3) + 8 * (r >> 2) + 4 * hi;
      int col = h * 256 + wn * 128 + nt * 32 + l31;
      attn_out[((size_t)b * S_LEN + row) * 2048 + col] = f2bf(acc[nt][r] * linv[r]);
    }
}

extern "C" void kernel_launch(void* const* d_in, const int* in_sizes, int n_in,
                              void* d_out, int out_size, void* d_ws, size_t ws_size,
                              hipStream_t stream) {
  const float* x = (const float*)d_in[0];
  const int* pos = (const int*)d_in[1];
  const float* wdq = (const float*)d_in[2];
  const float* bdq = (const float*)d_in[3];
  const float* qnw = (const float*)d_in[4];
  const float* wuq = (const float*)d_in[5];
  const float* buq = (const float*)d_in[6];
  const float* wdkv = (const float*)d_in[7];
  const float* bdkv = (const float*)d_in[8];
  const float* kvnw = (const float*)d_in[9];
  const float* wukv = (const float*)d_in[10];
  const float* bukv = (const float*)d_in[11];
  const float* wo = (const float*)d_in[12];
  const float* bo = (const float*)d_in[13];
  float* out = (float*)d_out;

  char* ws = (char*)d_ws;
  size_t off = 0;
  auto alloc = [&](size_t bytes) {
    char* p = ws + off;
    off += (bytes + 255) & ~(size_t)255;
    return p;
  };
  // vT (16.78MB) aliases xbf+t0+qout (22MB): all dead before k_vt runs
  u16* xbf = (u16*)alloc((size_t)R_TOK * 1024 * 2);    // dead after gemm A
  float* t0 = (float*)alloc((size_t)R_TOK * 320 * 4);  // dead after stagea
  u16* qout = (u16*)alloc((size_t)R_TOK * 1024 * 2);   // dead after stageb
  u16* vT = (u16*)d_ws;                                // alias of the three above
  u16* waT = (u16*)alloc((size_t)384 * 1024 * 2);      // padded 320->384 rows
  float* biasA = (float*)alloc(320 * 4);
  u16* wQT = (u16*)alloc((size_t)1024 * 128 * 2);
  u16* wKVT = (u16*)alloc((size_t)2560 * 128 * 2);
  u16* wOT = (u16*)alloc((size_t)1024 * 2048 * 2);
  u16* cq = (u16*)alloc((size_t)R_TOK * 128 * 2);
  u16* ckv = (u16*)alloc((size_t)R_TOK * 128 * 2);
  u16* krope = (u16*)alloc((size_t)R_TOK * 64 * 2);
  u16* qst = (u16*)alloc((size_t)R_TOK * 1024 * 2);
  u16* kvb = (u16*)alloc((size_t)R_TOK * 2560 * 2);
  u16* attnb = (u16*)alloc((size_t)R_TOK * 2048 * 2);
  (void)ws_size; (void)n_in; (void)in_sizes; (void)out_size;

  k_prep<<<6913, 256, 0, stream>>>(x, xbf, wdq, wdkv, waT, wuq, wQT, wukv, wKVT, wo, wOT,
                                   bdq, bdkv, biasA);

  // stage A: x @ [w_dq | w_dkv_kr] -> t0 fp32
  k_gemm_bt<0><<<dim3(3, 32), 256, 0, stream>>>(xbf, waT, biasA, t0, R_TOK, 320, 1024);
  k_stagea<<<R_TOK, 128, 0, stream>>>(t0, qnw, kvnw, pos, cq, ckv, krope);
  // stage B: q up-proj, rope+scale+scatter
  k_gemm_bt<1><<<dim3(8, 32), 256, 0, stream>>>(cq, wQT, buq, qout, R_TOK, 1024, 128);
  k_stageb<<<R_TOK, 256, 0, stream>>>(qout, pos, qst);
  // kv up-proj
  k_gemm_bt<1><<<dim3(20, 32), 256, 0, stream>>>(ckv, wKVT, bukv, kvb, R_TOK, 2560, 128);
  // V transpose (permuted-k layout); xbf/t0/qout dead here
  k_vt<<<dim3(4, 64, 16), 256, 0, stream>>>(kvb, vT);
  // attention: 512 blocks (2/CU -> 8 waves/CU), 256 threads, 64 q-rows/block
  k_attn<<<dim3(16, 32), 256, 0, stream>>>(qst, kvb, krope, vT, attnb);
  // output projection -> fp32 out
  k_gemm_bt<0><<<dim3(8, 32), 256, 0, stream>>>(attnb, wOT, bo, out, R_TOK, 1024, 2048);
}

// Round 10
// 284.889 us; speedup vs baseline: 1.3927x; 1.2119x over previous
//
#include <hip/hip_runtime.h>
#include <hip/hip_bf16.h>
#include <stdint.h>

typedef unsigned short u16;
typedef short short8 __attribute__((ext_vector_type(8)));
typedef float floatx4 __attribute__((ext_vector_type(4)));

#define S_LEN 2048
#define NB 2
#define NH 8
#define R_TOK (NB * S_LEN)  // 4096

#define L2_THETA 13.287712379549449f
// attention scale folded into Q, log2 domain: (1/sqrt(128)) * log2(e)
#define QSCALE (0.08838834764831845f * 1.4426950408889634f)

__device__ inline u16 f2bf(float f) {
  union { float f; uint32_t u; } x; x.f = f;
  uint32_t r = (x.u + 0x7fffu + ((x.u >> 16) & 1u)) >> 16;
  return (u16)r;
}
__device__ inline float bf2f(u16 h) {
  union { uint32_t u; float f; } x; x.u = ((uint32_t)h) << 16;
  return x.f;
}
__device__ inline floatx4 mfma16(short8 a, short8 b, floatx4 c) {
  return __builtin_amdgcn_mfma_f32_16x16x32_bf16(a, b, c, 0, 0, 0);
}
__device__ inline uint32_t pkbf(float a, float b) {
  union { __hip_bfloat162 h; uint32_t u; } c;
  c.h = __float22bfloat162_rn(make_float2(a, b));
  return c.u;
}
__device__ __forceinline__ void cp16(const void* g, const void* l) {
  __builtin_amdgcn_global_load_lds(
      (const __attribute__((address_space(1))) uint32_t*)(uintptr_t)g,
      (__attribute__((address_space(3))) uint32_t*)(uintptr_t)l, 16, 0, 0);
}

// ---------------- fused prep: x->bf16, weight transposes, bias concat ----------------
__global__ __launch_bounds__(256) void k_prep(
    const float* __restrict__ x, u16* __restrict__ xbf,
    const float* __restrict__ wdq, const float* __restrict__ wdkv, u16* __restrict__ waT,
    const float* __restrict__ wuq, u16* __restrict__ wQT,
    const float* __restrict__ wukv, u16* __restrict__ wKVT,
    const float* __restrict__ wo, u16* __restrict__ wOT,
    const float* __restrict__ bdq, const float* __restrict__ bdkv,
    float* __restrict__ biasA) {
  __shared__ u16 tile[32][33];
  const int s = blockIdx.x, tid = threadIdx.x;
  const int tx = tid & 31, ty = tid >> 5;
  if (s < 4096) {
    int i = s * 256 + tid;
    float4 v = ((const float4*)x)[i];
    ushort4 o;
    o.x = f2bf(v.x); o.y = f2bf(v.y); o.z = f2bf(v.z); o.w = f2bf(v.w);
    ((ushort4*)xbf)[i] = o;
  } else if (s < 4416) {  // waT: logical [1024][320] -> [320][1024]
    int t = s - 4096, bx = t % 10, by = t / 10;
    int c0 = bx * 32, r0 = by * 32;
#pragma unroll
    for (int i = 0; i < 4; ++i) {
      int r = r0 + ty + i * 8, c = c0 + tx;
      float v = (c < 128) ? wdq[(size_t)r * 128 + c] : wdkv[(size_t)r * 192 + (c - 128)];
      tile[ty + i * 8][tx] = f2bf(v);
    }
    __syncthreads();
#pragma unroll
    for (int i = 0; i < 4; ++i)
      waT[(size_t)(c0 + ty + i * 8) * 1024 + r0 + tx] = tile[tx][ty + i * 8];
  } else {
    const float* in; u16* out; int R, C, bx, by;
    if (s < 4544) { int t = s - 4416; in = wuq; out = wQT; R = 128; C = 1024; bx = t & 31; by = t >> 5; }
    else if (s < 4864) { int t = s - 4544; in = wukv; out = wKVT; R = 128; C = 2560; bx = t % 80; by = t / 80; }
    else if (s < 6912) { int t = s - 4864; in = wo; out = wOT; R = 2048; C = 1024; bx = t & 31; by = t >> 5; }
    else {
      if (tid < 320) biasA[tid] = (tid < 128) ? bdq[tid] : bdkv[tid - 128];
      return;
    }
    int c0 = bx * 32, r0 = by * 32;
#pragma unroll
    for (int i = 0; i < 4; ++i)
      tile[ty + i * 8][tx] = f2bf(in[(size_t)(r0 + ty + i * 8) * C + c0 + tx]);
    __syncthreads();
#pragma unroll
    for (int i = 0; i < 4; ++i)
      out[(size_t)(c0 + ty + i * 8) * R + r0 + tx] = tile[tx][ty + i * 8];
  }
}

// ---------------- 128x128-tile GEMM, B transposed [N][K], double-buffered async ----------
template <int OUT_BF>
__global__ __launch_bounds__(256) void k_gemm_bt(const u16* __restrict__ A,
                                                 const u16* __restrict__ BT,
                                                 const float* __restrict__ bias,
                                                 void* __restrict__ Cout,
                                                 int M, int N, int K) {
  __shared__ __align__(16) u16 Alds[2][128 * 32];
  __shared__ __align__(16) u16 Blds[2][128 * 32];
  const int tid = threadIdx.x;
  const int wave = tid >> 6, lane = tid & 63;
  const int lane15 = lane & 15, quad = lane >> 4;
  const int m0 = blockIdx.y * 128, n0 = blockIdx.x * 128;
  const int mw = (wave & 1) * 64, nw = (wave >> 1) * 64;

  floatx4 acc[4][4];
#pragma unroll
  for (int a = 0; a < 4; ++a)
#pragma unroll
    for (int b = 0; b < 4; ++b) acc[a][b] = (floatx4){0.f, 0.f, 0.f, 0.f};

  const int srow = wave * 32 + (lane >> 2);
  const int scol = (lane & 3) * 8;

  auto stage = [&](int k0, int buf) {
    const u16* ga = A + (size_t)(m0 + srow) * K + k0 + scol;
    cp16(ga, Alds[buf] + srow * 32 + scol);
    cp16(ga + (size_t)16 * K, Alds[buf] + (srow + 16) * 32 + scol);
    const u16* gb = BT + (size_t)(n0 + srow) * K + k0 + scol;
    cp16(gb, Blds[buf] + srow * 32 + scol);
    cp16(gb + (size_t)16 * K, Blds[buf] + (srow + 16) * 32 + scol);
  };

  stage(0, 0);
  int cur = 0;
  for (int k0 = 0; k0 < K; k0 += 32) {
    __syncthreads();
    if (k0 + 32 < K) stage(k0 + 32, cur ^ 1);
    short8 af[4], bf[4];
#pragma unroll
    for (int im = 0; im < 4; ++im)
      af[im] = *(const short8*)&Alds[cur][(mw + im * 16 + lane15) * 32 + quad * 8];
#pragma unroll
    for (int in = 0; in < 4; ++in)
      bf[in] = *(const short8*)&Blds[cur][(nw + in * 16 + lane15) * 32 + quad * 8];
#pragma unroll
    for (int im = 0; im < 4; ++im)
#pragma unroll
      for (int in = 0; in < 4; ++in) acc[im][in] = mfma16(af[im], bf[in], acc[im][in]);
    cur ^= 1;
  }

#pragma unroll
  for (int im = 0; im < 4; ++im)
#pragma unroll
    for (int in = 0; in < 4; ++in)
#pragma unroll
      for (int r = 0; r < 4; ++r) {
        int row = m0 + mw + im * 16 + quad * 4 + r;
        int col = n0 + nw + in * 16 + lane15;
        if (col < N) {
          float v = acc[im][in][r] + bias[col];
          if (OUT_BF)
            ((u16*)Cout)[(size_t)row * N + col] = f2bf(v);
          else
            ((float*)Cout)[(size_t)row * N + col] = v;
        }
      }
}

// ---------------- stage-A epilogue: rmsnorm(cq), rmsnorm(ckv), rope(k_rope) ----------------
__global__ void k_stagea(const float* __restrict__ t0, const float* __restrict__ qnw,
                         const float* __restrict__ kvnw, const int* __restrict__ pos_ids,
                         u16* __restrict__ cq, u16* __restrict__ ckv,
                         u16* __restrict__ krope) {
  int r = blockIdx.x, tid = threadIdx.x;  // 128 threads
  const float* row = t0 + (size_t)r * 320;
  float a = row[tid];
  float b = row[128 + tid];
  float sa = a * a, sb = b * b;
#pragma unroll
  for (int d = 1; d < 64; d <<= 1) {
    sa += __shfl_xor(sa, d);
    sb += __shfl_xor(sb, d);
  }
  __shared__ float red[4];
  if ((tid & 63) == 0) { red[(tid >> 6) * 2] = sa; red[(tid >> 6) * 2 + 1] = sb; }
  __syncthreads();
  sa = red[0] + red[2];
  sb = red[1] + red[3];
  float ra = rsqrtf(sa * (1.0f / 128.0f) + 1e-8f);
  float rb = rsqrtf(sb * (1.0f / 128.0f) + 1e-8f);
  cq[(size_t)r * 128 + tid] = f2bf(qnw[tid] * a * ra);
  ckv[(size_t)r * 128 + tid] = f2bf(kvnw[tid] * b * rb);
  if (tid < 32) {
    float xe = row[256 + 2 * tid], xo = row[256 + 2 * tid + 1];
    float p = (float)pos_ids[r];
    float freq = exp2f(-(2.0f * tid / 64.0f) * L2_THETA);
    float ang = p * freq;
    float c = cosf(ang), s = sinf(ang);
    krope[(size_t)r * 64 + 2 * tid] = f2bf(xe * c - xo * s);
    krope[(size_t)r * 64 + 2 * tid + 1] = f2bf(xe * s + xo * c);
  }
}

// ---------------- stage-B epilogue: rope(q_rope) + scale + scatter ----------------
__global__ void k_stageb(const u16* __restrict__ q, const int* __restrict__ pos_ids,
                         u16* __restrict__ qstates) {
  int r = blockIdx.x, tid = threadIdx.x;  // 256 threads
  int b = r >> 11, s = r & (S_LEN - 1);
  float p = (float)pos_ids[r];
#pragma unroll
  for (int i = 0; i < 4; ++i) {
    int idx = tid + i * 256;
    int h = idx >> 7, d = idx & 127;
    float val;
    if (d < 96) {
      val = bf2f(q[(size_t)r * 1024 + h * 96 + d]);
    } else {
      int j = d - 96, pr = j >> 1;
      float xe = bf2f(q[(size_t)r * 1024 + 768 + h * 32 + 2 * pr]);
      float xo = bf2f(q[(size_t)r * 1024 + 768 + h * 32 + 2 * pr + 1]);
      float freq = exp2f(-(2.0f * pr / 32.0f) * L2_THETA);
      float ang = p * freq;
      float c = cosf(ang), sn = sinf(ang);
      val = (j & 1) ? (xe * sn + xo * c) : (xe * c - xo * sn);
    }
    qstates[((size_t)(b * NH + h) * S_LEN + s) * 128 + d] = f2bf(val * QSCALE);
  }
}

// ---------------- V transpose with the 16x16 PV k-permutation baked in ----------------
// vT[pair][n=256][p=2048]: within each 64-wide k-chunk, p = u*8 + i (u=unit, i=hw):
//   source k-offset = 32*(u>>2) + 16*(i>>2) + 4*(u&3) + (i&3)
// For a ushort4 store at p=a*4 (a in [0,16)): k_base = 32*(a>>3) + 16*(a&1) + 4*((a>>1)&3),
// elements are 4 consecutive source rows.
__global__ __launch_bounds__(256) void k_vt(const u16* __restrict__ kvb, u16* __restrict__ vT) {
  __shared__ u16 tile[64][40];
  const int nx = blockIdx.x;   // 0..7  (32-wide n tile)
  const int sy = blockIdx.y;   // 0..31 (64-wide s tile)
  const int pz = blockIdx.z;   // pair
  const int b = pz >> 3, h = pz & 7;
  const int tid = threadIdx.x;
  const int n0 = nx * 32, s0 = sy * 64;
  {
    int rr = tid >> 2, cc = (tid & 3) * 8;
    const u16* src = kvb + ((size_t)(b * S_LEN + s0 + rr)) * 2560 + 512 + h * 256 + n0 + cc;
    *(short8*)&tile[rr][cc] = *(const short8*)src;
  }
  __syncthreads();
#pragma unroll
  for (int j = 0; j < 2; ++j) {
    int e = tid * 2 + j;
    int n = e >> 4, a = e & 15;
    int sb = 32 * (a >> 3) + 16 * (a & 1) + 4 * ((a >> 1) & 3);
    ushort4 o;
    o.x = tile[sb][n]; o.y = tile[sb + 1][n]; o.z = tile[sb + 2][n]; o.w = tile[sb + 3][n];
    *(ushort4*)&vT[((size_t)(pz * 256 + n0 + n)) * 2048 + s0 + a * 4] = o;
  }
}

// ---------------- flash attention: 16x16x32 MFMA (round-5 structure), all-async V ----------
// Block = (b,h) x 64 q-rows, 4 waves (16 q each), 256 thr. K-chunk 64. LDS 48KB.
// K: r5-exact unit-major layout, single buffer, async cp16.
// V: cp16 from pre-permuted vT (no in-register transpose, no staging VGPRs).
// Schedule: A drains K(ch); issueV(ch); QK+softmax; B drains V(ch); issueK(ch+1); PV.
// NO min-waves launch bound (rounds 3/8: clamping below live set spills).
__global__ __launch_bounds__(256) void k_attn(const u16* __restrict__ qstates,
                                              const u16* __restrict__ kv,
                                              const u16* __restrict__ krope,
                                              const u16* __restrict__ vT,
                                              u16* __restrict__ attn_out) {
  const int pair = blockIdx.x;  // 0..15 (pair-major: XCD locality)
  const int qblk = blockIdx.y;  // 0..31
  const int b = pair >> 3, h = pair & 7;
  const int tid = threadIdx.x;
  const int wave = tid >> 6, lane = tid & 63;
  const int lane15 = lane & 15, quad = lane >> 4;

  __shared__ __align__(16) u16 Klds[64 * 128];  // 16 KB, unit-major (r5 layout)
  __shared__ __align__(16) u16 Vlds[256 * 64];  // 32 KB, slot = u ^ ((n^(n>>3))&7)

  const int qrow0 = qblk * 64 + wave * 16;
  short8 qfrag[4];
  {
    const u16* qb = qstates + ((size_t)(b * NH + h) * S_LEN + qrow0 + lane15) * 128 + quad * 8;
#pragma unroll
    for (int c = 0; c < 4; ++c) qfrag[c] = *(const short8*)(qb + c * 32);
  }

  floatx4 o_acc[16];
#pragma unroll
  for (int g = 0; g < 16; ++g) o_acc[g] = (floatx4){0.f, 0.f, 0.f, 0.f};
  float m_i = -1e30f, l_i = 0.f;  // per-lane; q-row = lane15 (replicated across quads)

  // K staging (r5-exact): wave covers rowgroup wave*16..+15; op j: units 4j+kul
  const int kul = lane >> 4;
  const u16* kp[4];
  int kstr[4];
#pragma unroll
  for (int j = 0; j < 4; ++j) {
    int u = 4 * j + kul;
    const u16* base;
    int str;
    if (u < 8) { base = kv + h * 64 + u * 8; str = 2560; }
    else { base = krope + (u - 8) * 8; str = 64; }
    kp[j] = base + (size_t)(b * S_LEN + wave * 16 + lane15) * str;
    kstr[j] = str;
  }
  auto issueK = [&]() {
#pragma unroll
    for (int j = 0; j < 4; ++j) {
      cp16(kp[j], Klds + ((wave * 16 + 4 * j) * 16 + lane) * 8);
      kp[j] += (size_t)64 * kstr[j];
    }
  };
  // V staging: 8 cp16/thread; op oi: n = oi*32 + (tid>>3), slot tid&7, unit = slot^swz(n)
  const int vn5 = tid >> 3, vsl = tid & 7;
  const u16* vp[8];
#pragma unroll
  for (int oi = 0; oi < 8; ++oi) {
    int n = oi * 32 + vn5;
    int u = vsl ^ ((n ^ (n >> 3)) & 7);
    vp[oi] = vT + ((size_t)pair * 256 + n) * 2048 + u * 8;
  }
  auto issueV = [&]() {
#pragma unroll
    for (int oi = 0; oi < 8; ++oi) {
      cp16(vp[oi], Vlds + ((size_t)(oi * 256 + tid)) * 8);
      vp[oi] += 64;
    }
  };

  issueK();  // K(0)

  for (int ch = 0; ch < S_LEN / 64; ++ch) {
    __syncthreads();  // A: K(ch) drained; V(ch-1) PV reads done
    issueV();         // V(ch) in flight across QK+softmax

    // S^T = K * Q^T : st[t][r] = S[q=lane15][k = t*16 + quad*4 + r] (log2 domain)
    floatx4 st[4];
#pragma unroll
    for (int t = 0; t < 4; ++t) st[t] = (floatx4){0.f, 0.f, 0.f, 0.f};
#pragma unroll
    for (int c = 0; c < 4; ++c) {
      short8 qf = qfrag[c];
#pragma unroll
      for (int t = 0; t < 4; ++t) {
        short8 kf = *(const short8*)&Klds[((t * 16 + c * 4 + quad) * 16 + lane15) * 8];
        st[t] = mfma16(kf, qf, st[t]);
      }
    }

    // online softmax (per-lane scalars, 2-shfl reduce, packed bf16 cvt)
    float mloc = st[0][0];
#pragma unroll
    for (int t = 0; t < 4; ++t)
#pragma unroll
      for (int r = 0; r < 4; ++r) mloc = fmaxf(mloc, st[t][r]);
    mloc = fmaxf(mloc, __shfl_xor(mloc, 16));
    mloc = fmaxf(mloc, __shfl_xor(mloc, 32));
    float mnew = fmaxf(m_i, mloc);
    float rs = 0.f;
    union { short8 s; uint4 u; } a01, a23;
    {
      float p0, p1, p2, p3;
      p0 = exp2f(st[0][0] - mnew); p1 = exp2f(st[0][1] - mnew);
      p2 = exp2f(st[0][2] - mnew); p3 = exp2f(st[0][3] - mnew);
      rs += (p0 + p1) + (p2 + p3);
      a01.u.x = pkbf(p0, p1); a01.u.y = pkbf(p2, p3);
      p0 = exp2f(st[1][0] - mnew); p1 = exp2f(st[1][1] - mnew);
      p2 = exp2f(st[1][2] - mnew); p3 = exp2f(st[1][3] - mnew);
      rs += (p0 + p1) + (p2 + p3);
      a01.u.z = pkbf(p0, p1); a01.u.w = pkbf(p2, p3);
      p0 = exp2f(st[2][0] - mnew); p1 = exp2f(st[2][1] - mnew);
      p2 = exp2f(st[2][2] - mnew); p3 = exp2f(st[2][3] - mnew);
      rs += (p0 + p1) + (p2 + p3);
      a23.u.x = pkbf(p0, p1); a23.u.y = pkbf(p2, p3);
      p0 = exp2f(st[3][0] - mnew); p1 = exp2f(st[3][1] - mnew);
      p2 = exp2f(st[3][2] - mnew); p3 = exp2f(st[3][3] - mnew);
      rs += (p0 + p1) + (p2 + p3);
      a23.u.z = pkbf(p0, p1); a23.u.w = pkbf(p2, p3);
    }
    rs += __shfl_xor(rs, 16);
    rs += __shfl_xor(rs, 32);

    if (__any(mloc > m_i)) {  // running max changed for some q-row: rescale
      float alpha = exp2f(m_i - mnew);
      l_i = l_i * alpha + rs;
      m_i = mnew;
      float al[4];
#pragma unroll
      for (int r = 0; r < 4; ++r) al[r] = __shfl(alpha, quad * 4 + r, 16);
#pragma unroll
      for (int g = 0; g < 16; ++g) {
        o_acc[g][0] *= al[0]; o_acc[g][1] *= al[1];
        o_acc[g][2] *= al[2]; o_acc[g][3] *= al[3];
      }
    } else {
      l_i += rs;
    }

    __syncthreads();  // B: V(ch) drained; K(ch) QK reads done
    if (ch + 1 < S_LEN / 64) issueK();  // K(ch+1) in flight across PV

    // PV: b-frags are single b128 reads (permuted-k vT layout)
#pragma unroll
    for (int g = 0; g < 16; ++g) {
      int n = g * 16 + lane15;
      int sw = (n ^ (n >> 3)) & 7;
      short8 b01 = *(const short8*)&Vlds[n * 64 + ((quad ^ sw) & 7) * 8];
      short8 b23 = *(const short8*)&Vlds[n * 64 + (((quad | 4) ^ sw) & 7) * 8];
      floatx4 o = o_acc[g];
      o = mfma16(a01.s, b01, o);
      o = mfma16(a23.s, b23, o);
      o_acc[g] = o;
    }
  }

  float rl = 1.0f / l_i;
  float linv[4];
#pragma unroll
  for (int r = 0; r < 4; ++r) linv[r] = __shfl(rl, quad * 4 + r, 16);
#pragma unroll
  for (int g = 0; g < 16; ++g) {
#pragma unroll
    for (int r = 0; r < 4; ++r) {
      int row = qrow0 + quad * 4 + r;
      int col = h * 256 + g * 16 + lane15;
      attn_out[((size_t)b * S_LEN + row) * 2048 + col] = f2bf(o_acc[g][r] * linv[r]);
    }
  }
}

extern "C" void kernel_launch(void* const* d_in, const int* in_sizes, int n_in,
                              void* d_out, int out_size, void* d_ws, size_t ws_size,
                              hipStream_t stream) {
  const float* x = (const float*)d_in[0];
  const int* pos = (const int*)d_in[1];
  const float* wdq = (const float*)d_in[2];
  const float* bdq = (const float*)d_in[3];
  const float* qnw = (const float*)d_in[4];
  const float* wuq = (const float*)d_in[5];
  const float* buq = (const float*)d_in[6];
  const float* wdkv = (const float*)d_in[7];
  const float* bdkv = (const float*)d_in[8];
  const float* kvnw = (const float*)d_in[9];
  const float* wukv = (const float*)d_in[10];
  const float* bukv = (const float*)d_in[11];
  const float* wo = (const float*)d_in[12];
  const float* bo = (const float*)d_in[13];
  float* out = (float*)d_out;

  char* ws = (char*)d_ws;
  size_t off = 0;
  auto alloc = [&](size_t bytes) {
    char* p = ws + off;
    off += (bytes + 255) & ~(size_t)255;
    return p;
  };
  // vT (16.78MB) aliases xbf+t0+qout (22MB): all dead before k_vt runs
  u16* xbf = (u16*)alloc((size_t)R_TOK * 1024 * 2);    // dead after gemm A
  float* t0 = (float*)alloc((size_t)R_TOK * 320 * 4);  // dead after stagea
  u16* qout = (u16*)alloc((size_t)R_TOK * 1024 * 2);   // dead after stageb
  u16* vT = (u16*)d_ws;                                // alias of the three above
  u16* waT = (u16*)alloc((size_t)384 * 1024 * 2);      // padded 320->384 rows
  float* biasA = (float*)alloc(320 * 4);
  u16* wQT = (u16*)alloc((size_t)1024 * 128 * 2);
  u16* wKVT = (u16*)alloc((size_t)2560 * 128 * 2);
  u16* wOT = (u16*)alloc((size_t)1024 * 2048 * 2);
  u16* cq = (u16*)alloc((size_t)R_TOK * 128 * 2);
  u16* ckv = (u16*)alloc((size_t)R_TOK * 128 * 2);
  u16* krope = (u16*)alloc((size_t)R_TOK * 64 * 2);
  u16* qst = (u16*)alloc((size_t)R_TOK * 1024 * 2);
  u16* kvb = (u16*)alloc((size_t)R_TOK * 2560 * 2);
  u16* attnb = (u16*)alloc((size_t)R_TOK * 2048 * 2);
  (void)ws_size; (void)n_in; (void)in_sizes; (void)out_size;

  k_prep<<<6913, 256, 0, stream>>>(x, xbf, wdq, wdkv, waT, wuq, wQT, wukv, wKVT, wo, wOT,
                                   bdq, bdkv, biasA);

  // stage A: x @ [w_dq | w_dkv_kr] -> t0 fp32
  k_gemm_bt<0><<<dim3(3, 32), 256, 0, stream>>>(xbf, waT, biasA, t0, R_TOK, 320, 1024);
  k_stagea<<<R_TOK, 128, 0, stream>>>(t0, qnw, kvnw, pos, cq, ckv, krope);
  // stage B: q up-proj, rope+scale+scatter
  k_gemm_bt<1><<<dim3(8, 32), 256, 0, stream>>>(cq, wQT, buq, qout, R_TOK, 1024, 128);
  k_stageb<<<R_TOK, 256, 0, stream>>>(qout, pos, qst);
  // kv up-proj
  k_gemm_bt<1><<<dim3(20, 32), 256, 0, stream>>>(ckv, wKVT, bukv, kvb, R_TOK, 2560, 128);
  // V transpose (16x16 permuted-k layout); xbf/t0/qout dead here
  k_vt<<<dim3(8, 32, 16), 256, 0, stream>>>(kvb, vT);
  // attention: 512 blocks (2/CU -> 8 waves/CU), 256 threads, 64 q-rows/block
  k_attn<<<dim3(16, 32), 256, 0, stream>>>(qst, kvb, krope, vT, attnb);
  // output projection -> fp32 out
  k_gemm_bt<0><<<dim3(8, 32), 256, 0, stream>>>(attnb, wOT, bo, out, R_TOK, 1024, 2048);
}